// Round 15
// baseline (200.505 us; speedup 1.0000x reference)
//
#include <hip/hip_runtime.h>
#include <hip/hip_bf16.h>

#define NN 50000
#define CIN 128
#define HH 4
#define DD 32
#define HD 128
#define EE 800000
#define NEG 0.2f

typedef unsigned short ushortT;
typedef unsigned int uintT;
typedef __attribute__((ext_vector_type(8))) short bf16x8;
typedef __attribute__((ext_vector_type(4))) float f32x4;
typedef unsigned int uint4v __attribute__((ext_vector_type(4)));

// ---------------------------------------------------------------------------
// ws layout (units of 4B):
//   [0]       : flag (1 = edge_index is int64, 0 = int32)
//   CNT_OFF  = 16       : per-node in-degree (excl self) (NN ints) [memset 0]
//   FILL_OFF = 50016    : scatter fill counters (NN ints)          [memset 0]
//   ROW_OFF  = 100032   : CSR row offsets (NN+1 ints)
//   ESRC_OFF = 150048   : dst-sorted src indices (EE ints)
//   BTOT_OFF = 1000048  : scan block totals (64 ints)
//   WBF_OFF  = 1000112  : W bf16 [256][128] (16384 float-slots)
//   XPH_OFF  = 1016496  : interleaved bf16 rows xl|xr [NN][256] (3.2M slots)
// ---------------------------------------------------------------------------
#define CNT_OFF  16
#define FILL_OFF 50016
#define ROW_OFF  100032
#define ESRC_OFF 150048
#define BTOT_OFF 1000048
#define WBF_OFF  1000112
#define XPH_OFF  1016496
#define SCAN_NB  49          // ceil((NN+1)/1024)

__device__ __forceinline__ ushortT f2bf(float f) {
    uintT u = __float_as_uint(f);
    u = (u + 0x7fff + ((u >> 16) & 1)) >> 16;   // RNE
    return (ushortT)u;
}
__device__ __forceinline__ float bflo(uintT u) { return __uint_as_float(u << 16); }
__device__ __forceinline__ float bfhi(uintT u) { return __uint_as_float(u & 0xffff0000u); }

// ---------------------------------------------------------------------------
// Detect int64 vs int32 edge_index: int64 values < 2^31 have zero odd words.
// ---------------------------------------------------------------------------
__global__ void detect_kernel(const int* __restrict__ ei_raw, int* __restrict__ flag)
{
    const int l = threadIdx.x;                // 64 threads
    const int w = ei_raw[2 * l + 1];
    const unsigned long long b = __ballot(w != 0);
    if (l == 0) flag[0] = (b == 0ULL) ? 1 : 0;
}

// histogram dst straight from raw edge index; 4 edges/thread (grid-stride)
__global__ __launch_bounds__(256) void hist_kernel(
    const int* __restrict__ ei_raw, const int* __restrict__ flag, int* __restrict__ cnt)
{
    const int t0 = blockIdx.x * 256 + threadIdx.x;
    const int stride = gridDim.x * 256;
    const int f = flag[0];
    #pragma unroll
    for (int k = 0; k < 4; ++k) {
        const int e = t0 + k * stride;
        if (e < EE) {
            const int d = f ? ei_raw[2 * (EE + e)] : ei_raw[EE + e];
            atomicAdd(&cnt[d], 1);
        }
    }
}

// convert Wl|Wr to bf16: wbf[256][128], rows 0..127 = Wl, 128..255 = Wr
__global__ __launch_bounds__(256) void wprep_kernel(
    const float* __restrict__ Wl, const float* __restrict__ Wr, ushortT* __restrict__ wbf)
{
    const int i = blockIdx.x * 256 + threadIdx.x;   // 4096 threads, 8 elems each
    const float* src = (i < 2048) ? Wl : Wr;
    const int off = (i < 2048) ? i : i - 2048;
    const float4 v0 = *(const float4*)(src + (size_t)off * 8);
    const float4 v1 = *(const float4*)(src + (size_t)off * 8 + 4);
    bf16x8 o;
    o[0] = f2bf(v0.x); o[1] = f2bf(v0.y); o[2] = f2bf(v0.z); o[3] = f2bf(v0.w);
    o[4] = f2bf(v1.x); o[5] = f2bf(v1.y); o[6] = f2bf(v1.z); o[7] = f2bf(v1.w);
    *(bf16x8*)(wbf + ((i < 2048) ? 0 : 16384) + (size_t)off * 8) = o;
}

// ---------------------------------------------------------------------------
// scan1: block-local exclusive scan of cnt (self-loops handled inline later)
// ---------------------------------------------------------------------------
__global__ __launch_bounds__(1024) void scan1_kernel(
    const int* __restrict__ cnt, int* __restrict__ row, int* __restrict__ btot)
{
    __shared__ int wtot[16];
    const int t = threadIdx.x, lane = t & 63, wv = t >> 6;
    const int i = blockIdx.x * 1024 + t;
    const int v = (i < NN) ? cnt[i] : 0;
    int acc = v;
    #pragma unroll
    for (int off = 1; off < 64; off <<= 1) {
        const int u = __shfl_up(acc, off, 64);
        if (lane >= off) acc += u;
    }
    if (lane == 63) wtot[wv] = acc;
    __syncthreads();
    if (wv == 0 && lane < 16) {
        const int wvv = wtot[lane];
        int wacc = wvv;
        #pragma unroll
        for (int off = 1; off < 16; off <<= 1) {
            const int u = __shfl_up(wacc, off, 64);
            if (lane >= off) wacc += u;
        }
        wtot[lane] = wacc - wvv;            // exclusive wave offset
    }
    __syncthreads();
    const int ex = wtot[wv] + acc - v;      // block-local exclusive prefix
    if (i <= NN) row[i] = ex;
    if (t == 1023) btot[blockIdx.x] = ex + v;
}

// scan3: each block wave-reduces its own btot prefix, adds to row
__global__ __launch_bounds__(256) void scan3_kernel(
    int* __restrict__ row, const int* __restrict__ btot)
{
    const int i = blockIdx.x * 256 + threadIdx.x;
    const int chunk = blockIdx.x >> 2;              // 1024-chunk id (const per block)
    const int lane = threadIdx.x & 63;
    int v = (lane < chunk) ? btot[lane] : 0;
    #pragma unroll
    for (int off = 1; off < 64; off <<= 1) v += __shfl_xor(v, off);
    if (i <= NN) row[i] += v;
}

// place src of each real edge into its dst segment; 4 edges/thread
__global__ __launch_bounds__(256) void scatter_kernel(
    const int* __restrict__ ei_raw, const int* __restrict__ flag,
    const int* __restrict__ row, int* __restrict__ fill, int* __restrict__ esrc)
{
    const int t0 = blockIdx.x * 256 + threadIdx.x;
    const int stride = gridDim.x * 256;
    const int f = flag[0];
    #pragma unroll
    for (int k = 0; k < 4; ++k) {
        const int e = t0 + k * stride;
        if (e < EE) {
            int s, d;
            if (f) { s = ei_raw[2 * e]; d = ei_raw[2 * (EE + e)]; }
            else   { s = ei_raw[e];     d = ei_raw[EE + e]; }
            const int pos = row[d] + atomicAdd(&fill[d], 1);
            esrc[pos] = s;
        }
    }
}

// ---------------------------------------------------------------------------
// MFMA GEMM with fused f32->bf16 x conversion via LDS staging.
// Block = 256 thr = 4 waves; computes 32 rows x 256 cols (all parts/halves).
// ---------------------------------------------------------------------------
__global__ __launch_bounds__(256) void gemm_mfma_kernel(
    const float* __restrict__ x, const ushortT* __restrict__ wbf,
    ushortT* __restrict__ xph)
{
    __shared__ ushortT xa[32][136];       // 8.7 KB staging, 272B rows (16B aligned)
    __shared__ ushortT tl[4][32][72];     // 18.4 KB epilogue transpose
    const int t = threadIdx.x;
    const int row0 = blockIdx.x * 32;

    {
        const int r = t >> 3, seg = t & 7;
        const int gr = row0 + r;
        const int gr_c = gr < NN ? gr : NN - 1;
        const float* src = x + (size_t)gr_c * CIN + seg * 16;
        const float4 v0 = *(const float4*)(src);
        const float4 v1 = *(const float4*)(src + 4);
        const float4 v2 = *(const float4*)(src + 8);
        const float4 v3 = *(const float4*)(src + 12);
        bf16x8 o0, o1;
        o0[0] = f2bf(v0.x); o0[1] = f2bf(v0.y); o0[2] = f2bf(v0.z); o0[3] = f2bf(v0.w);
        o0[4] = f2bf(v1.x); o0[5] = f2bf(v1.y); o0[6] = f2bf(v1.z); o0[7] = f2bf(v1.w);
        o1[0] = f2bf(v2.x); o1[1] = f2bf(v2.y); o1[2] = f2bf(v2.z); o1[3] = f2bf(v2.w);
        o1[4] = f2bf(v3.x); o1[5] = f2bf(v3.y); o1[6] = f2bf(v3.z); o1[7] = f2bf(v3.w);
        *(bf16x8*)(&xa[r][seg * 16]) = o0;
        *(bf16x8*)(&xa[r][seg * 16 + 8]) = o1;
    }
    __syncthreads();

    const int w = t >> 6, l = t & 63;
    const int part = w >> 1, ch = w & 1;
    const int rowlo = l & 15, kb = (l >> 4) * 8;

    bf16x8 a[2][4];
    #pragma unroll
    for (int rg = 0; rg < 2; ++rg)
        #pragma unroll
        for (int ks = 0; ks < 4; ++ks)
            a[rg][ks] = *(const bf16x8*)(&xa[rg * 16 + rowlo][ks * 32 + kb]);

    f32x4 acc[2][4] = {};
    const ushortT* wbase = wbf + (size_t)(part * 128 + ch * 64 + rowlo) * 128 + kb;
    #pragma unroll
    for (int ks = 0; ks < 4; ++ks) {
        #pragma unroll
        for (int ct = 0; ct < 4; ++ct) {
            const bf16x8 b = *(const bf16x8*)(wbase + (size_t)ct * 16 * 128 + ks * 32);
            acc[0][ct] = __builtin_amdgcn_mfma_f32_16x16x32_bf16(a[0][ks], b, acc[0][ct], 0, 0, 0);
            acc[1][ct] = __builtin_amdgcn_mfma_f32_16x16x32_bf16(a[1][ks], b, acc[1][ct], 0, 0, 0);
        }
    }

    #pragma unroll
    for (int rg = 0; rg < 2; ++rg)
        #pragma unroll
        for (int ct = 0; ct < 4; ++ct)
            #pragma unroll
            for (int j = 0; j < 4; ++j)
                tl[w][rg * 16 + (l >> 4) * 4 + j][ct * 16 + rowlo] = f2bf(acc[rg][ct][j]);
    __syncthreads();

    #pragma unroll
    for (int c = 0; c < 4; ++c) {
        const int cid = c * 256 + t;
        const int r = cid >> 5, col = (cid & 31) * 8;
        const int gr = row0 + r;
        if (gr < NN)
            *(bf16x8*)(xph + (size_t)gr * 256 + col) =
                *(const bf16x8*)(&tl[col >> 6][r][col & 63]);
    }
}

// ---------------------------------------------------------------------------
// Fused per-node GATv2, EDGE-PAIR layout: one wave per node; each 16B/lane
// wave-load covers TWO edges' full 512B xph rows (A: lanes 0-31, B: 32-63).
// Within a half: lanes q=0..15 hold xl (dims q*8..+7, head q>>2) -> score;
// lanes q=16..31 hold xr -> aggregate. 0.5 VMEM instr/edge vs 2 before.
// ---------------------------------------------------------------------------
#define PROC_PAIR(vv, MB)                                                 \
    {                                                                     \
        float f[8];                                                       \
        _Pragma("unroll")                                                 \
        for (int j = 0; j < 4; ++j) {                                     \
            f[2*j]   = bflo((vv)[j]);                                     \
            f[2*j+1] = bfhi((vv)[j]);                                     \
        }                                                                 \
        float c = 0.f;                                                    \
        _Pragma("unroll")                                                 \
        for (int j = 0; j < 8; ++j) {                                     \
            float t2 = f[j] + rn[j];                                      \
            t2 = t2 > 0.f ? t2 : NEG * t2;                                \
            c = fmaf(at[j], t2, c);                                       \
        }                                                                 \
        c += __shfl_xor(c, 1);                                            \
        c += __shfl_xor(c, 2);                                            \
        const float e = __expf(c) * (MB);                                 \
        den += e;                                                         \
        const float eh = __shfl(e, ehsrc);                                \
        _Pragma("unroll")                                                 \
        for (int j = 0; j < 8; ++j) acc[j] = fmaf(eh, f[j], acc[j]);      \
    }

__global__ __launch_bounds__(256) void gat_node_kernel(
    const int* __restrict__ row, const int* __restrict__ esrc,
    const ushortT* __restrict__ xph, const float* __restrict__ att,
    const float* __restrict__ bias, float* __restrict__ out)
{
    const int l = threadIdx.x & 63;
    const int half = l >> 5;            // 0 = edge A, 1 = edge B
    const int q = l & 31;
    const int qm = q & 15;              // dim-block within xl/xr part
    const int n = blockIdx.x * 4 + (threadIdx.x >> 6);
    if (n >= NN) return;

    // att for dims qm*8..+7 (meaningful on score lanes; att is [H][D]=128 f32)
    float at[8];
    #pragma unroll
    for (int j = 0; j < 8; ++j) at[j] = att[qm * 8 + j];

    // xr[n] dims qm*8..+7 (the "+ Wr h_dst" term)
    float rn[8];
    {
        const uint4v r8 = *(const uint4v*)(xph + (size_t)n * 256 + 128 + qm * 8);
        #pragma unroll
        for (int j = 0; j < 4; ++j) { rn[2*j] = bflo(r8[j]); rn[2*j+1] = bfhi(r8[j]); }
    }
    // alpha source lane: head base within my half's score lanes
    const int ehsrc = (l & 32) | (((q & 15) >> 2) << 2);

    float den = 0.f, acc[8];
    #pragma unroll
    for (int j = 0; j < 8; ++j) acc[j] = 0.f;

    // self-loop as a pair (A = n, B masked to 0)
    {
        const uint4v v = *(const uint4v*)(xph + (size_t)n * 256 + q * 8);
        const float mb = half ? 0.f : 1.f;
        PROC_PAIR(v, mb)
    }

    const int p0 = row[n], p1 = row[n + 1];
    int p = p0;

    for (; p + 8 <= p1; p += 8) {       // 4 pairs = 8 edges
        int s[4];
        #pragma unroll
        for (int u = 0; u < 4; ++u) s[u] = esrc[p + 2 * u + half];
        uint4v v[4];
        #pragma unroll
        for (int u = 0; u < 4; ++u)
            v[u] = *(const uint4v*)(xph + (size_t)s[u] * 256 + q * 8);
        PROC_PAIR(v[0], 1.f) PROC_PAIR(v[1], 1.f)
        PROC_PAIR(v[2], 1.f) PROC_PAIR(v[3], 1.f)
    }
    for (; p + 2 <= p1; p += 2) {       // one pair
        const int s = esrc[p + half];
        const uint4v v = *(const uint4v*)(xph + (size_t)s * 256 + q * 8);
        PROC_PAIR(v, 1.f)
    }
    if (p < p1) {                        // lone edge in A half
        const int s = esrc[p];
        const uint4v v = *(const uint4v*)(xph + (size_t)s * 256 + q * 8);
        const float mb = half ? 0.f : 1.f;
        PROC_PAIR(v, mb)
    }

    // combine halves: den meaningful on lanes 0-15; acc on lanes 16-31
    den += __shfl_xor(den, 32);
    #pragma unroll
    for (int j = 0; j < 8; ++j) acc[j] += __shfl_xor(acc[j], 32);

    // per-head normalize (agg lanes fetch their head's den from lanes 0,4,8,12)
    const float dh = __shfl(den, ((q & 15) >> 2) << 2);
    const float inv = 1.f / fmaxf(dh, 1e-16f);
    #pragma unroll
    for (int j = 0; j < 8; ++j) acc[j] *= inv;

    // mean over heads: agg lane 16+(4h+w) holds head h, dims w*8..+7
    #pragma unroll
    for (int j = 0; j < 8; ++j) {
        acc[j] += __shfl_xor(acc[j], 4);
        acc[j] += __shfl_xor(acc[j], 8);
    }

    if (l >= 16 && l < 20) {            // 4 lanes write the 32-float out row
        const int w = l - 16;
        #pragma unroll
        for (int j = 0; j < 8; ++j)
            out[(size_t)n * DD + w * 8 + j] = acc[j] * 0.25f + bias[w * 8 + j];
    }
}

extern "C" void kernel_launch(void* const* d_in, const int* in_sizes, int n_in,
                              void* d_out, int out_size, void* d_ws, size_t ws_size,
                              hipStream_t stream)
{
    const float* x    = (const float*)d_in[0];
    const int*   ei   = (const int*)d_in[1];
    const float* Wl   = (const float*)d_in[2];
    const float* Wr   = (const float*)d_in[3];
    const float* att  = (const float*)d_in[4];
    const float* bias = (const float*)d_in[5];
    float* out = (float*)d_out;

    float*   ws   = (float*)d_ws;
    int*     flag = (int*)ws;
    int*     cnt  = (int*)(ws + CNT_OFF);
    int*     fill = (int*)(ws + FILL_OFF);
    int*     row  = (int*)(ws + ROW_OFF);
    int*     esrc = (int*)(ws + ESRC_OFF);
    int*     btot = (int*)(ws + BTOT_OFF);
    ushortT* wbf  = (ushortT*)(ws + WBF_OFF);
    ushortT* xph  = (ushortT*)(ws + XPH_OFF);

    // zero cnt + fill (contiguous 400 KB)
    hipMemsetAsync(cnt, 0, (size_t)(2 * NN) * sizeof(int), stream);

    hipLaunchKernelGGL(detect_kernel, dim3(1), dim3(64), 0, stream, ei, flag);
    hipLaunchKernelGGL(hist_kernel, dim3((EE + 1023) / 1024), dim3(256), 0, stream,
                       ei, flag, cnt);
    hipLaunchKernelGGL(wprep_kernel, dim3(16), dim3(256), 0, stream, Wl, Wr, wbf);
    hipLaunchKernelGGL(scan1_kernel, dim3(SCAN_NB), dim3(1024), 0, stream, cnt, row, btot);
    hipLaunchKernelGGL(scan3_kernel, dim3((NN + 256) / 256), dim3(256), 0, stream, row, btot);
    hipLaunchKernelGGL(scatter_kernel, dim3((EE + 1023) / 1024), dim3(256), 0, stream,
                       ei, flag, row, fill, esrc);
    hipLaunchKernelGGL(gemm_mfma_kernel, dim3((NN + 31) / 32), dim3(256), 0, stream,
                       x, wbf, xph);
    hipLaunchKernelGGL(gat_node_kernel, dim3((NN + 3) / 4), dim3(256), 0, stream,
                       row, esrc, xph, att, bias, out);
}

// Round 16
// 176.579 us; speedup vs baseline: 1.1355x; 1.1355x over previous
//
#include <hip/hip_runtime.h>
#include <hip/hip_bf16.h>

#define NN 50000
#define CIN 128
#define HH 4
#define DD 32
#define HD 128
#define EE 800000
#define NEG 0.2f

typedef unsigned short ushortT;
typedef unsigned int uintT;
typedef __attribute__((ext_vector_type(8))) short bf16x8;
typedef __attribute__((ext_vector_type(4))) float f32x4;

// ---------------------------------------------------------------------------
// ws layout (units of 4B):
//   CNT_OFF  = 16       : per-node in-degree (excl self) (NN ints) [memset 0]
//   FILL_OFF = 50016    : scatter fill counters (NN ints)          [memset 0]
//   ROW_OFF  = 100032   : CSR row offsets, block-local (NN+1 ints)
//   ESRC_OFF = 150048   : dst-sorted src indices (EE ints)
//   BTOT_OFF = 1000048  : scan block totals -> exclusive prefix (64 ints)
//   WBF_OFF  = 1000112  : W bf16 [256][128] (16384 float-slots)
//   XPH_OFF  = 1016496  : interleaved bf16 rows xl|xr [NN][256] (3.2M slots)
// ---------------------------------------------------------------------------
#define CNT_OFF  16
#define FILL_OFF 50016
#define ROW_OFF  100032
#define ESRC_OFF 150048
#define BTOT_OFF 1000048
#define WBF_OFF  1000112
#define XPH_OFF  1016496
#define SCAN_NB  49          // ceil((NN+1)/1024)
#define GEMM_NB  1563        // (NN+31)/32
#define HIST_NB  782         // ceil(EE / (256*4))

__device__ __forceinline__ ushortT f2bf(float f) {
    uintT u = __float_as_uint(f);
    u = (u + 0x7fff + ((u >> 16) & 1)) >> 16;   // RNE
    return (ushortT)u;
}
__device__ __forceinline__ float bflo(uintT u) { return __uint_as_float(u << 16); }
__device__ __forceinline__ float bfhi(uintT u) { return __uint_as_float(u & 0xffff0000u); }

// convert Wl|Wr to bf16: wbf[256][128], rows 0..127 = Wl, 128..255 = Wr
__global__ __launch_bounds__(256) void wprep_kernel(
    const float* __restrict__ Wl, const float* __restrict__ Wr, ushortT* __restrict__ wbf)
{
    const int i = blockIdx.x * 256 + threadIdx.x;   // 4096 threads, 8 elems each
    const float* src = (i < 2048) ? Wl : Wr;
    const int off = (i < 2048) ? i : i - 2048;
    const float4 v0 = *(const float4*)(src + (size_t)off * 8);
    const float4 v1 = *(const float4*)(src + (size_t)off * 8 + 4);
    bf16x8 o;
    o[0] = f2bf(v0.x); o[1] = f2bf(v0.y); o[2] = f2bf(v0.z); o[3] = f2bf(v0.w);
    o[4] = f2bf(v1.x); o[5] = f2bf(v1.y); o[6] = f2bf(v1.z); o[7] = f2bf(v1.w);
    *(bf16x8*)(wbf + ((i < 2048) ? 0 : 16384) + (size_t)off * 8) = o;
}

// ---------------------------------------------------------------------------
// COMBO: blocks [0,GEMM_NB) = MFMA gemm (x@Wl^T | x@Wr^T -> xph);
//        blocks [GEMM_NB, GEMM_NB+HIST_NB) = dst histogram (inline detect).
// Independent work overlapped in one launch. LDS 18.4 KB (staging aliased
// with epilogue buffer) -> 8 blocks/CU for both paths.
// ---------------------------------------------------------------------------
__global__ __launch_bounds__(256) void combo_kernel(
    const float* __restrict__ x, const ushortT* __restrict__ wbf,
    ushortT* __restrict__ xph, const int* __restrict__ ei_raw,
    int* __restrict__ cnt)
{
    __shared__ ushortT smem[9216];        // 18.4 KB: xa[32][136] then tl[4][32][72]
    __shared__ int sflag;
    const int t = threadIdx.x;

    if (blockIdx.x >= GEMM_NB) {
        // ---- histogram path ----
        if (t < 64) {
            const int w = ei_raw[2 * t + 1];
            const unsigned long long b = __ballot(w != 0);
            if (t == 0) sflag = (b == 0ULL) ? 1 : 0;
        }
        __syncthreads();
        const int f = sflag;
        const int t0 = (blockIdx.x - GEMM_NB) * 256 + t;
        const int stride = HIST_NB * 256;
        #pragma unroll
        for (int k = 0; k < 4; ++k) {
            const int e = t0 + k * stride;
            if (e < EE) {
                const int d = f ? ei_raw[2 * (EE + e)] : ei_raw[EE + e];
                atomicAdd(&cnt[d], 1);
            }
        }
        return;
    }

    // ---- gemm path ----
    ushortT (*xa)[136] = (ushortT(*)[136])smem;          // 4352 ushorts
    ushortT (*tl)[32][72] = (ushortT(*)[32][72])smem;    // 9216 ushorts (aliased)
    const int row0 = blockIdx.x * 32;

    {   // stage + convert 32 rows of x
        const int r = t >> 3, seg = t & 7;
        const int gr = row0 + r;
        const int gr_c = gr < NN ? gr : NN - 1;
        const float* src = x + (size_t)gr_c * CIN + seg * 16;
        const float4 v0 = *(const float4*)(src);
        const float4 v1 = *(const float4*)(src + 4);
        const float4 v2 = *(const float4*)(src + 8);
        const float4 v3 = *(const float4*)(src + 12);
        bf16x8 o0, o1;
        o0[0] = f2bf(v0.x); o0[1] = f2bf(v0.y); o0[2] = f2bf(v0.z); o0[3] = f2bf(v0.w);
        o0[4] = f2bf(v1.x); o0[5] = f2bf(v1.y); o0[6] = f2bf(v1.z); o0[7] = f2bf(v1.w);
        o1[0] = f2bf(v2.x); o1[1] = f2bf(v2.y); o1[2] = f2bf(v2.z); o1[3] = f2bf(v2.w);
        o1[4] = f2bf(v3.x); o1[5] = f2bf(v3.y); o1[6] = f2bf(v3.z); o1[7] = f2bf(v3.w);
        *(bf16x8*)(&xa[r][seg * 16]) = o0;
        *(bf16x8*)(&xa[r][seg * 16 + 8]) = o1;
    }
    __syncthreads();

    const int w = t >> 6, l = t & 63;
    const int part = w >> 1, ch = w & 1;
    const int rowlo = l & 15, kb = (l >> 4) * 8;

    bf16x8 a[2][4];
    #pragma unroll
    for (int rg = 0; rg < 2; ++rg)
        #pragma unroll
        for (int ks = 0; ks < 4; ++ks)
            a[rg][ks] = *(const bf16x8*)(&xa[rg * 16 + rowlo][ks * 32 + kb]);
    __syncthreads();    // all xa reads done before tl overwrites the buffer

    f32x4 acc[2][4] = {};
    const ushortT* wbase = wbf + (size_t)(part * 128 + ch * 64 + rowlo) * 128 + kb;
    #pragma unroll
    for (int ks = 0; ks < 4; ++ks) {
        #pragma unroll
        for (int ct = 0; ct < 4; ++ct) {
            const bf16x8 b = *(const bf16x8*)(wbase + (size_t)ct * 16 * 128 + ks * 32);
            acc[0][ct] = __builtin_amdgcn_mfma_f32_16x16x32_bf16(a[0][ks], b, acc[0][ct], 0, 0, 0);
            acc[1][ct] = __builtin_amdgcn_mfma_f32_16x16x32_bf16(a[1][ks], b, acc[1][ct], 0, 0, 0);
        }
    }

    #pragma unroll
    for (int rg = 0; rg < 2; ++rg)
        #pragma unroll
        for (int ct = 0; ct < 4; ++ct)
            #pragma unroll
            for (int j = 0; j < 4; ++j)
                tl[w][rg * 16 + (l >> 4) * 4 + j][ct * 16 + rowlo] = f2bf(acc[rg][ct][j]);
    __syncthreads();

    #pragma unroll
    for (int c = 0; c < 4; ++c) {
        const int cid = c * 256 + t;
        const int r = cid >> 5, col = (cid & 31) * 8;
        const int gr = row0 + r;
        if (gr < NN)
            *(bf16x8*)(xph + (size_t)gr * 256 + col) =
                *(const bf16x8*)(&tl[col >> 6][r][col & 63]);
    }
}

// ---------------------------------------------------------------------------
// scan1: block-local exclusive scan of cnt; btot[b] = block total
// ---------------------------------------------------------------------------
__global__ __launch_bounds__(1024) void scan1_kernel(
    const int* __restrict__ cnt, int* __restrict__ row, int* __restrict__ btot)
{
    __shared__ int wtot[16];
    const int t = threadIdx.x, lane = t & 63, wv = t >> 6;
    const int i = blockIdx.x * 1024 + t;
    const int v = (i < NN) ? cnt[i] : 0;
    int acc = v;
    #pragma unroll
    for (int off = 1; off < 64; off <<= 1) {
        const int u = __shfl_up(acc, off, 64);
        if (lane >= off) acc += u;
    }
    if (lane == 63) wtot[wv] = acc;
    __syncthreads();
    if (wv == 0 && lane < 16) {
        const int wvv = wtot[lane];
        int wacc = wvv;
        #pragma unroll
        for (int off = 1; off < 16; off <<= 1) {
            const int u = __shfl_up(wacc, off, 64);
            if (lane >= off) wacc += u;
        }
        wtot[lane] = wacc - wvv;            // exclusive wave offset
    }
    __syncthreads();
    const int ex = wtot[wv] + acc - v;      // block-local exclusive prefix
    if (i <= NN) row[i] = ex;
    if (t == 1023) btot[blockIdx.x] = ex + v;
}

// scan2: btot -> exclusive prefix (1 block, 64 threads)
__global__ void scan2_kernel(int* __restrict__ btot)
{
    const int lane = threadIdx.x;
    const int v = (lane < SCAN_NB) ? btot[lane] : 0;
    int acc = v;
    #pragma unroll
    for (int off = 1; off < 64; off <<= 1) {
        const int u = __shfl_up(acc, off, 64);
        if (lane >= off) acc += u;
    }
    if (lane < SCAN_NB) btot[lane] = acc - v;          // exclusive
}

// place src of each real edge into its dst segment; inline detect; 4/thread
__global__ __launch_bounds__(256) void scatter_kernel(
    const int* __restrict__ ei_raw, const int* __restrict__ row,
    const int* __restrict__ btot, int* __restrict__ fill, int* __restrict__ esrc)
{
    __shared__ int sflag;
    const int t = threadIdx.x;
    if (t < 64) {
        const int w = ei_raw[2 * t + 1];
        const unsigned long long b = __ballot(w != 0);
        if (t == 0) sflag = (b == 0ULL) ? 1 : 0;
    }
    __syncthreads();
    const int f = sflag;
    const int t0 = blockIdx.x * 256 + t;
    const int stride = gridDim.x * 256;
    #pragma unroll
    for (int k = 0; k < 4; ++k) {
        const int e = t0 + k * stride;
        if (e < EE) {
            int s, d;
            if (f) { s = ei_raw[2 * e]; d = ei_raw[2 * (EE + e)]; }
            else   { s = ei_raw[e];     d = ei_raw[EE + e]; }
            const int pos = row[d] + btot[d >> 10] + atomicAdd(&fill[d], 1);
            esrc[pos] = s;
        }
    }
}

// ---------------------------------------------------------------------------
// Fused per-node GATv2 (r12-proven): one wave per node, lane = h*16+dd,
// self-loop inline, main loop unrolled 8 (16 gathers in flight).
// ---------------------------------------------------------------------------
#define SCORE_OF(ulv, cv)                                                 \
    {                                                                     \
        float vx = bflo(ulv) + rnx, vy = bfhi(ulv) + rny;                 \
        vx = vx > 0.f ? vx : NEG * vx;                                    \
        vy = vy > 0.f ? vy : NEG * vy;                                    \
        cv = vx * a2.x + vy * a2.y;                                       \
    }
#define RED16(cv)                                                         \
    cv += __shfl_xor(cv, 1); cv += __shfl_xor(cv, 2);                     \
    cv += __shfl_xor(cv, 4); cv += __shfl_xor(cv, 8);

#define GROUP4(i0, i1, i2, i3)                                            \
    {                                                                     \
        float c0, c1, c2, c3;                                             \
        SCORE_OF(ul[i0], c0) SCORE_OF(ul[i1], c1)                         \
        SCORE_OF(ul[i2], c2) SCORE_OF(ul[i3], c3)                         \
        c0 += __shfl_xor(c0, 1); c1 += __shfl_xor(c1, 1);                 \
        c2 += __shfl_xor(c2, 1); c3 += __shfl_xor(c3, 1);                 \
        c0 += __shfl_xor(c0, 2); c1 += __shfl_xor(c1, 2);                 \
        c2 += __shfl_xor(c2, 2); c3 += __shfl_xor(c3, 2);                 \
        c0 += __shfl_xor(c0, 4); c1 += __shfl_xor(c1, 4);                 \
        c2 += __shfl_xor(c2, 4); c3 += __shfl_xor(c3, 4);                 \
        c0 += __shfl_xor(c0, 8); c1 += __shfl_xor(c1, 8);                 \
        c2 += __shfl_xor(c2, 8); c3 += __shfl_xor(c3, 8);                 \
        const float e0 = __expf(c0), e1 = __expf(c1);                     \
        const float e2 = __expf(c2), e3 = __expf(c3);                     \
        den += (e0 + e1) + (e2 + e3);                                     \
        ax = fmaf(e0, bflo(us[i0]), ax); ay = fmaf(e0, bfhi(us[i0]), ay); \
        ax = fmaf(e1, bflo(us[i1]), ax); ay = fmaf(e1, bfhi(us[i1]), ay); \
        ax = fmaf(e2, bflo(us[i2]), ax); ay = fmaf(e2, bfhi(us[i2]), ay); \
        ax = fmaf(e3, bflo(us[i3]), ax); ay = fmaf(e3, bfhi(us[i3]), ay); \
    }

__global__ __launch_bounds__(256) void gat_node_kernel(
    const int* __restrict__ row, const int* __restrict__ btot,
    const int* __restrict__ esrc, const ushortT* __restrict__ xph,
    const float* __restrict__ att, const float* __restrict__ bias,
    float* __restrict__ out)
{
    const int lane = threadIdx.x & 63;
    const int h = lane >> 4, dd = lane & 15;
    const int n = blockIdx.x * 4 + (threadIdx.x >> 6);
    if (n >= NN) return;

    const float2 a2 = *(const float2*)(att + h * DD + dd * 2);
    const uintT uln = *(const uintT*)(xph + (size_t)n * 256 + lane * 2);
    const uintT urn = *(const uintT*)(xph + (size_t)n * 256 + 128 + lane * 2);
    const float rnx = bflo(urn), rny = bfhi(urn);

    // self-loop first
    float den, ax, ay;
    {
        float c;
        SCORE_OF(uln, c)
        RED16(c)
        const float pe = __expf(c);
        den = pe;
        ax = pe * bflo(urn);
        ay = pe * bfhi(urn);
    }

    const int p0 = row[n] + btot[n >> 10];
    const int p1 = row[n + 1] + btot[(n + 1) >> 10];
    int p = p0;

    for (; p + 8 <= p1; p += 8) {
        int s[8];
        #pragma unroll
        for (int j = 0; j < 8; ++j) s[j] = esrc[p + j];
        uintT ul[8], us[8];
        #pragma unroll
        for (int j = 0; j < 8; ++j) {
            ul[j] = *(const uintT*)(xph + (size_t)s[j] * 256 + lane * 2);
            us[j] = *(const uintT*)(xph + (size_t)s[j] * 256 + 128 + lane * 2);
        }
        GROUP4(0, 1, 2, 3) GROUP4(4, 5, 6, 7)
    }
    for (; p + 4 <= p1; p += 4) {
        int s[4];
        #pragma unroll
        for (int j = 0; j < 4; ++j) s[j] = esrc[p + j];
        uintT ul[4], us[4];
        #pragma unroll
        for (int j = 0; j < 4; ++j) {
            ul[j] = *(const uintT*)(xph + (size_t)s[j] * 256 + lane * 2);
            us[j] = *(const uintT*)(xph + (size_t)s[j] * 256 + 128 + lane * 2);
        }
        GROUP4(0, 1, 2, 3)
    }
    for (; p < p1; ++p) {
        const int s = esrc[p];
        const uintT ul = *(const uintT*)(xph + (size_t)s * 256 + lane * 2);
        const uintT us = *(const uintT*)(xph + (size_t)s * 256 + 128 + lane * 2);
        float c;
        SCORE_OF(ul, c)
        RED16(c)
        const float pe = __expf(c);
        den += pe;
        ax = fmaf(pe, bflo(us), ax);
        ay = fmaf(pe, bfhi(us), ay);
    }

    const float inv = 1.f / fmaxf(den, 1e-16f);
    ax *= inv; ay *= inv;
    ax += __shfl_xor(ax, 16); ay += __shfl_xor(ay, 16);
    ax += __shfl_xor(ax, 32); ay += __shfl_xor(ay, 32);
    if (h == 0) {
        float2 o;
        o.x = ax * 0.25f + bias[dd * 2];
        o.y = ay * 0.25f + bias[dd * 2 + 1];
        *(float2*)(out + (size_t)n * DD + dd * 2) = o;
    }
}

extern "C" void kernel_launch(void* const* d_in, const int* in_sizes, int n_in,
                              void* d_out, int out_size, void* d_ws, size_t ws_size,
                              hipStream_t stream)
{
    const float* x    = (const float*)d_in[0];
    const int*   ei   = (const int*)d_in[1];
    const float* Wl   = (const float*)d_in[2];
    const float* Wr   = (const float*)d_in[3];
    const float* att  = (const float*)d_in[4];
    const float* bias = (const float*)d_in[5];
    float* out = (float*)d_out;

    float*   ws   = (float*)d_ws;
    int*     cnt  = (int*)(ws + CNT_OFF);
    int*     fill = (int*)(ws + FILL_OFF);
    int*     row  = (int*)(ws + ROW_OFF);
    int*     esrc = (int*)(ws + ESRC_OFF);
    int*     btot = (int*)(ws + BTOT_OFF);
    ushortT* wbf  = (ushortT*)(ws + WBF_OFF);
    ushortT* xph  = (ushortT*)(ws + XPH_OFF);

    // zero cnt + fill (contiguous 400 KB)
    hipMemsetAsync(cnt, 0, (size_t)(2 * NN) * sizeof(int), stream);

    hipLaunchKernelGGL(wprep_kernel, dim3(16), dim3(256), 0, stream, Wl, Wr, wbf);
    hipLaunchKernelGGL(combo_kernel, dim3(GEMM_NB + HIST_NB), dim3(256), 0, stream,
                       x, wbf, xph, ei, cnt);
    hipLaunchKernelGGL(scan1_kernel, dim3(SCAN_NB), dim3(1024), 0, stream, cnt, row, btot);
    hipLaunchKernelGGL(scan2_kernel, dim3(1), dim3(64), 0, stream, btot);
    hipLaunchKernelGGL(scatter_kernel, dim3((EE + 1023) / 1024), dim3(256), 0, stream,
                       ei, row, btot, fill, esrc);
    hipLaunchKernelGGL(gat_node_kernel, dim3((NN + 3) / 4), dim3(256), 0, stream,
                       row, btot, esrc, xph, att, bias, out);
}

// Round 17
// 172.567 us; speedup vs baseline: 1.1619x; 1.0232x over previous
//
#include <hip/hip_runtime.h>
#include <hip/hip_bf16.h>

#define NN 50000
#define CIN 128
#define HH 4
#define DD 32
#define HD 128
#define EE 800000
#define NEG 0.2f

typedef unsigned short ushortT;
typedef unsigned int uintT;
typedef __attribute__((ext_vector_type(8))) short bf16x8;
typedef __attribute__((ext_vector_type(4))) float f32x4;

// ---------------------------------------------------------------------------
// ws layout (units of 4B):
//   CNT_OFF  = 16       : per-node in-degree (excl self) (NN ints) [memset 0]
//   FILL_OFF = 50016    : scatter fill counters (NN ints)          [memset 0]
//   ROW_OFF  = 100032   : CSR row offsets, block-local (NN+1 ints)
//   ESRC_OFF = 150048   : dst-sorted src indices (EE ints)
//   BTOT_OFF = 1000048  : scan block totals -> exclusive prefix (64 ints)
//   WBF_OFF  = 1000112  : W bf16 [256][128] (16384 float-slots)
//   XPH_OFF  = 1016496  : interleaved bf16 rows xl|xr [NN][256] (3.2M slots)
// ---------------------------------------------------------------------------
#define CNT_OFF  16
#define FILL_OFF 50016
#define ROW_OFF  100032
#define ESRC_OFF 150048
#define BTOT_OFF 1000048
#define WBF_OFF  1000112
#define XPH_OFF  1016496
#define SCAN_NB  49          // ceil((NN+1)/1024)
#define GEMM_NB  1563        // (NN+31)/32
#define SCAT_NB  3125        // EE / 256

__device__ __forceinline__ ushortT f2bf(float f) {
    uintT u = __float_as_uint(f);
    u = (u + 0x7fff + ((u >> 16) & 1)) >> 16;   // RNE
    return (ushortT)u;
}
__device__ __forceinline__ float bflo(uintT u) { return __uint_as_float(u << 16); }
__device__ __forceinline__ float bfhi(uintT u) { return __uint_as_float(u & 0xffff0000u); }

// convert Wl|Wr to bf16: wbf[256][128], rows 0..127 = Wl, 128..255 = Wr
__global__ __launch_bounds__(256) void wprep_kernel(
    const float* __restrict__ Wl, const float* __restrict__ Wr, ushortT* __restrict__ wbf)
{
    const int i = blockIdx.x * 256 + threadIdx.x;   // 4096 threads, 8 elems each
    const float* src = (i < 2048) ? Wl : Wr;
    const int off = (i < 2048) ? i : i - 2048;
    const float4 v0 = *(const float4*)(src + (size_t)off * 8);
    const float4 v1 = *(const float4*)(src + (size_t)off * 8 + 4);
    bf16x8 o;
    o[0] = f2bf(v0.x); o[1] = f2bf(v0.y); o[2] = f2bf(v0.z); o[3] = f2bf(v0.w);
    o[4] = f2bf(v1.x); o[5] = f2bf(v1.y); o[6] = f2bf(v1.z); o[7] = f2bf(v1.w);
    *(bf16x8*)(wbf + ((i < 2048) ? 0 : 16384) + (size_t)off * 8) = o;
}

// dst histogram, 1 edge/thread (max TLP for L2 atomics); inline int64 detect
__global__ __launch_bounds__(256) void hist_kernel(
    const int* __restrict__ ei_raw, int* __restrict__ cnt)
{
    __shared__ int sflag;
    const int t = threadIdx.x;
    if (t < 64) {
        const int w = ei_raw[2 * t + 1];
        const unsigned long long b = __ballot(w != 0);
        if (t == 0) sflag = (b == 0ULL) ? 1 : 0;
    }
    __syncthreads();
    const int e = blockIdx.x * 256 + t;
    if (e < EE) {
        const int d = sflag ? ei_raw[2 * (EE + e)] : ei_raw[EE + e];
        atomicAdd(&cnt[d], 1);
    }
}

// ---------------------------------------------------------------------------
// scan1: block-local exclusive scan of cnt; btot[b] = block total
// ---------------------------------------------------------------------------
__global__ __launch_bounds__(1024) void scan1_kernel(
    const int* __restrict__ cnt, int* __restrict__ row, int* __restrict__ btot)
{
    __shared__ int wtot[16];
    const int t = threadIdx.x, lane = t & 63, wv = t >> 6;
    const int i = blockIdx.x * 1024 + t;
    const int v = (i < NN) ? cnt[i] : 0;
    int acc = v;
    #pragma unroll
    for (int off = 1; off < 64; off <<= 1) {
        const int u = __shfl_up(acc, off, 64);
        if (lane >= off) acc += u;
    }
    if (lane == 63) wtot[wv] = acc;
    __syncthreads();
    if (wv == 0 && lane < 16) {
        const int wvv = wtot[lane];
        int wacc = wvv;
        #pragma unroll
        for (int off = 1; off < 16; off <<= 1) {
            const int u = __shfl_up(wacc, off, 64);
            if (lane >= off) wacc += u;
        }
        wtot[lane] = wacc - wvv;            // exclusive wave offset
    }
    __syncthreads();
    const int ex = wtot[wv] + acc - v;      // block-local exclusive prefix
    if (i <= NN) row[i] = ex;
    if (t == 1023) btot[blockIdx.x] = ex + v;
}

// scan2: btot -> exclusive prefix (1 block, 64 threads)
__global__ void scan2_kernel(int* __restrict__ btot)
{
    const int lane = threadIdx.x;
    const int v = (lane < SCAN_NB) ? btot[lane] : 0;
    int acc = v;
    #pragma unroll
    for (int off = 1; off < 64; off <<= 1) {
        const int u = __shfl_up(acc, off, 64);
        if (lane >= off) acc += u;
    }
    if (lane < SCAN_NB) btot[lane] = acc - v;          // exclusive
}

// ---------------------------------------------------------------------------
// COMBO2: blocks [0,GEMM_NB) = MFMA gemm; [GEMM_NB, +SCAT_NB) = scatter
// (1 edge/thread). Independent halves overlapped in one launch.
// ---------------------------------------------------------------------------
__global__ __launch_bounds__(256) void combo2_kernel(
    const float* __restrict__ x, const ushortT* __restrict__ wbf,
    ushortT* __restrict__ xph, const int* __restrict__ ei_raw,
    const int* __restrict__ row, const int* __restrict__ btot,
    int* __restrict__ fill, int* __restrict__ esrc)
{
    __shared__ ushortT smem[9216];        // 18.4 KB: xa[32][136] then tl[4][32][72]
    __shared__ int sflag;
    const int t = threadIdx.x;

    if (blockIdx.x >= GEMM_NB) {
        // ---- scatter path: place src of each edge into its dst segment ----
        if (t < 64) {
            const int w = ei_raw[2 * t + 1];
            const unsigned long long b = __ballot(w != 0);
            if (t == 0) sflag = (b == 0ULL) ? 1 : 0;
        }
        __syncthreads();
        const int e = (blockIdx.x - GEMM_NB) * 256 + t;
        if (e < EE) {
            int s, d;
            if (sflag) { s = ei_raw[2 * e]; d = ei_raw[2 * (EE + e)]; }
            else       { s = ei_raw[e];     d = ei_raw[EE + e]; }
            const int pos = row[d] + btot[d >> 10] + atomicAdd(&fill[d], 1);
            esrc[pos] = s;
        }
        return;
    }

    // ---- gemm path ----
    ushortT (*xa)[136] = (ushortT(*)[136])smem;          // 4352 ushorts
    ushortT (*tl)[32][72] = (ushortT(*)[32][72])smem;    // 9216 ushorts (aliased)
    const int row0 = blockIdx.x * 32;

    {   // stage + convert 32 rows of x
        const int r = t >> 3, seg = t & 7;
        const int gr = row0 + r;
        const int gr_c = gr < NN ? gr : NN - 1;
        const float* src = x + (size_t)gr_c * CIN + seg * 16;
        const float4 v0 = *(const float4*)(src);
        const float4 v1 = *(const float4*)(src + 4);
        const float4 v2 = *(const float4*)(src + 8);
        const float4 v3 = *(const float4*)(src + 12);
        bf16x8 o0, o1;
        o0[0] = f2bf(v0.x); o0[1] = f2bf(v0.y); o0[2] = f2bf(v0.z); o0[3] = f2bf(v0.w);
        o0[4] = f2bf(v1.x); o0[5] = f2bf(v1.y); o0[6] = f2bf(v1.z); o0[7] = f2bf(v1.w);
        o1[0] = f2bf(v2.x); o1[1] = f2bf(v2.y); o1[2] = f2bf(v2.z); o1[3] = f2bf(v2.w);
        o1[4] = f2bf(v3.x); o1[5] = f2bf(v3.y); o1[6] = f2bf(v3.z); o1[7] = f2bf(v3.w);
        *(bf16x8*)(&xa[r][seg * 16]) = o0;
        *(bf16x8*)(&xa[r][seg * 16 + 8]) = o1;
    }
    __syncthreads();

    const int w = t >> 6, l = t & 63;
    const int part = w >> 1, ch = w & 1;
    const int rowlo = l & 15, kb = (l >> 4) * 8;

    bf16x8 a[2][4];
    #pragma unroll
    for (int rg = 0; rg < 2; ++rg)
        #pragma unroll
        for (int ks = 0; ks < 4; ++ks)
            a[rg][ks] = *(const bf16x8*)(&xa[rg * 16 + rowlo][ks * 32 + kb]);
    __syncthreads();    // all xa reads done before tl overwrites the buffer

    f32x4 acc[2][4] = {};
    const ushortT* wbase = wbf + (size_t)(part * 128 + ch * 64 + rowlo) * 128 + kb;
    #pragma unroll
    for (int ks = 0; ks < 4; ++ks) {
        #pragma unroll
        for (int ct = 0; ct < 4; ++ct) {
            const bf16x8 b = *(const bf16x8*)(wbase + (size_t)ct * 16 * 128 + ks * 32);
            acc[0][ct] = __builtin_amdgcn_mfma_f32_16x16x32_bf16(a[0][ks], b, acc[0][ct], 0, 0, 0);
            acc[1][ct] = __builtin_amdgcn_mfma_f32_16x16x32_bf16(a[1][ks], b, acc[1][ct], 0, 0, 0);
        }
    }

    #pragma unroll
    for (int rg = 0; rg < 2; ++rg)
        #pragma unroll
        for (int ct = 0; ct < 4; ++ct)
            #pragma unroll
            for (int j = 0; j < 4; ++j)
                tl[w][rg * 16 + (l >> 4) * 4 + j][ct * 16 + rowlo] = f2bf(acc[rg][ct][j]);
    __syncthreads();

    #pragma unroll
    for (int c = 0; c < 4; ++c) {
        const int cid = c * 256 + t;
        const int r = cid >> 5, col = (cid & 31) * 8;
        const int gr = row0 + r;
        if (gr < NN)
            *(bf16x8*)(xph + (size_t)gr * 256 + col) =
                *(const bf16x8*)(&tl[col >> 6][r][col & 63]);
    }
}

// ---------------------------------------------------------------------------
// Fused per-node GATv2 (r12-proven): one wave per node, lane = h*16+dd,
// self-loop inline, main loop unrolled 8 (16 gathers in flight).
// ---------------------------------------------------------------------------
#define SCORE_OF(ulv, cv)                                                 \
    {                                                                     \
        float vx = bflo(ulv) + rnx, vy = bfhi(ulv) + rny;                 \
        vx = vx > 0.f ? vx : NEG * vx;                                    \
        vy = vy > 0.f ? vy : NEG * vy;                                    \
        cv = vx * a2.x + vy * a2.y;                                       \
    }
#define RED16(cv)                                                         \
    cv += __shfl_xor(cv, 1); cv += __shfl_xor(cv, 2);                     \
    cv += __shfl_xor(cv, 4); cv += __shfl_xor(cv, 8);

#define GROUP4(i0, i1, i2, i3)                                            \
    {                                                                     \
        float c0, c1, c2, c3;                                             \
        SCORE_OF(ul[i0], c0) SCORE_OF(ul[i1], c1)                         \
        SCORE_OF(ul[i2], c2) SCORE_OF(ul[i3], c3)                         \
        c0 += __shfl_xor(c0, 1); c1 += __shfl_xor(c1, 1);                 \
        c2 += __shfl_xor(c2, 1); c3 += __shfl_xor(c3, 1);                 \
        c0 += __shfl_xor(c0, 2); c1 += __shfl_xor(c1, 2);                 \
        c2 += __shfl_xor(c2, 2); c3 += __shfl_xor(c3, 2);                 \
        c0 += __shfl_xor(c0, 4); c1 += __shfl_xor(c1, 4);                 \
        c2 += __shfl_xor(c2, 4); c3 += __shfl_xor(c3, 4);                 \
        c0 += __shfl_xor(c0, 8); c1 += __shfl_xor(c1, 8);                 \
        c2 += __shfl_xor(c2, 8); c3 += __shfl_xor(c3, 8);                 \
        const float e0 = __expf(c0), e1 = __expf(c1);                     \
        const float e2 = __expf(c2), e3 = __expf(c3);                     \
        den += (e0 + e1) + (e2 + e3);                                     \
        ax = fmaf(e0, bflo(us[i0]), ax); ay = fmaf(e0, bfhi(us[i0]), ay); \
        ax = fmaf(e1, bflo(us[i1]), ax); ay = fmaf(e1, bfhi(us[i1]), ay); \
        ax = fmaf(e2, bflo(us[i2]), ax); ay = fmaf(e2, bfhi(us[i2]), ay); \
        ax = fmaf(e3, bflo(us[i3]), ax); ay = fmaf(e3, bfhi(us[i3]), ay); \
    }

__global__ __launch_bounds__(256) void gat_node_kernel(
    const int* __restrict__ row, const int* __restrict__ btot,
    const int* __restrict__ esrc, const ushortT* __restrict__ xph,
    const float* __restrict__ att, const float* __restrict__ bias,
    float* __restrict__ out)
{
    const int lane = threadIdx.x & 63;
    const int h = lane >> 4, dd = lane & 15;
    const int n = blockIdx.x * 4 + (threadIdx.x >> 6);
    if (n >= NN) return;

    const float2 a2 = *(const float2*)(att + h * DD + dd * 2);
    const uintT uln = *(const uintT*)(xph + (size_t)n * 256 + lane * 2);
    const uintT urn = *(const uintT*)(xph + (size_t)n * 256 + 128 + lane * 2);
    const float rnx = bflo(urn), rny = bfhi(urn);

    // self-loop first
    float den, ax, ay;
    {
        float c;
        SCORE_OF(uln, c)
        RED16(c)
        const float pe = __expf(c);
        den = pe;
        ax = pe * bflo(urn);
        ay = pe * bfhi(urn);
    }

    const int p0 = row[n] + btot[n >> 10];
    const int p1 = row[n + 1] + btot[(n + 1) >> 10];
    int p = p0;

    for (; p + 8 <= p1; p += 8) {
        int s[8];
        #pragma unroll
        for (int j = 0; j < 8; ++j) s[j] = esrc[p + j];
        uintT ul[8], us[8];
        #pragma unroll
        for (int j = 0; j < 8; ++j) {
            ul[j] = *(const uintT*)(xph + (size_t)s[j] * 256 + lane * 2);
            us[j] = *(const uintT*)(xph + (size_t)s[j] * 256 + 128 + lane * 2);
        }
        GROUP4(0, 1, 2, 3) GROUP4(4, 5, 6, 7)
    }
    for (; p + 4 <= p1; p += 4) {
        int s[4];
        #pragma unroll
        for (int j = 0; j < 4; ++j) s[j] = esrc[p + j];
        uintT ul[4], us[4];
        #pragma unroll
        for (int j = 0; j < 4; ++j) {
            ul[j] = *(const uintT*)(xph + (size_t)s[j] * 256 + lane * 2);
            us[j] = *(const uintT*)(xph + (size_t)s[j] * 256 + 128 + lane * 2);
        }
        GROUP4(0, 1, 2, 3)
    }
    for (; p < p1; ++p) {
        const int s = esrc[p];
        const uintT ul = *(const uintT*)(xph + (size_t)s * 256 + lane * 2);
        const uintT us = *(const uintT*)(xph + (size_t)s * 256 + 128 + lane * 2);
        float c;
        SCORE_OF(ul, c)
        RED16(c)
        const float pe = __expf(c);
        den += pe;
        ax = fmaf(pe, bflo(us), ax);
        ay = fmaf(pe, bfhi(us), ay);
    }

    const float inv = 1.f / fmaxf(den, 1e-16f);
    ax *= inv; ay *= inv;
    ax += __shfl_xor(ax, 16); ay += __shfl_xor(ay, 16);
    ax += __shfl_xor(ax, 32); ay += __shfl_xor(ay, 32);
    if (h == 0) {
        float2 o;
        o.x = ax * 0.25f + bias[dd * 2];
        o.y = ay * 0.25f + bias[dd * 2 + 1];
        *(float2*)(out + (size_t)n * DD + dd * 2) = o;
    }
}

extern "C" void kernel_launch(void* const* d_in, const int* in_sizes, int n_in,
                              void* d_out, int out_size, void* d_ws, size_t ws_size,
                              hipStream_t stream)
{
    const float* x    = (const float*)d_in[0];
    const int*   ei   = (const int*)d_in[1];
    const float* Wl   = (const float*)d_in[2];
    const float* Wr   = (const float*)d_in[3];
    const float* att  = (const float*)d_in[4];
    const float* bias = (const float*)d_in[5];
    float* out = (float*)d_out;

    float*   ws   = (float*)d_ws;
    int*     cnt  = (int*)(ws + CNT_OFF);
    int*     fill = (int*)(ws + FILL_OFF);
    int*     row  = (int*)(ws + ROW_OFF);
    int*     esrc = (int*)(ws + ESRC_OFF);
    int*     btot = (int*)(ws + BTOT_OFF);
    ushortT* wbf  = (ushortT*)(ws + WBF_OFF);
    ushortT* xph  = (ushortT*)(ws + XPH_OFF);

    // zero cnt + fill (contiguous 400 KB)
    hipMemsetAsync(cnt, 0, (size_t)(2 * NN) * sizeof(int), stream);

    hipLaunchKernelGGL(wprep_kernel, dim3(16), dim3(256), 0, stream, Wl, Wr, wbf);
    hipLaunchKernelGGL(hist_kernel, dim3(SCAT_NB), dim3(256), 0, stream, ei, cnt);
    hipLaunchKernelGGL(scan1_kernel, dim3(SCAN_NB), dim3(1024), 0, stream, cnt, row, btot);
    hipLaunchKernelGGL(scan2_kernel, dim3(1), dim3(64), 0, stream, btot);
    hipLaunchKernelGGL(combo2_kernel, dim3(GEMM_NB + SCAT_NB), dim3(256), 0, stream,
                       x, wbf, xph, ei, row, btot, fill, esrc);
    hipLaunchKernelGGL(gat_node_kernel, dim3((NN + 3) / 4), dim3(256), 0, stream,
                       row, btot, esrc, xph, att, bias, out);
}

// Round 18
// 138.840 us; speedup vs baseline: 1.4441x; 1.2429x over previous
//
#include <hip/hip_runtime.h>
#include <hip/hip_bf16.h>

#define NN 50000
#define CIN 128
#define HH 4
#define DD 32
#define HD 128
#define EE 800000
#define NEG 0.2f

typedef unsigned short ushortT;
typedef unsigned int uintT;
typedef __attribute__((ext_vector_type(8))) short bf16x8;
typedef __attribute__((ext_vector_type(4))) float f32x4;

// ---------------------------------------------------------------------------
// ws layout (units of 4B):
//   CNT_OFF  = 16       : per-node in-degree (excl self) (NN ints) [memset 0]
//   ROW_OFF  = 50016    : CSR row offsets, block-local (NN+1 ints)
//   RANK_OFF = 100032   : per-edge rank within dst segment (EE ints)
//   ESRC_OFF = 900048   : dst-sorted src indices (EE ints)
//   BTOT_OFF = 1700064  : scan block totals -> exclusive prefix (64 ints)
//   WBF_OFF  = 1700128  : W bf16 [256][128] (16384 float-slots)
//   XPH_OFF  = 1716512  : interleaved bf16 rows xl|xr [NN][256] (3.2M slots)
// total ~4.92M floats = 19.7 MB
// ---------------------------------------------------------------------------
#define CNT_OFF  16
#define ROW_OFF  50016
#define RANK_OFF 100032
#define ESRC_OFF 900048
#define BTOT_OFF 1700064
#define WBF_OFF  1700128
#define XPH_OFF  1716512
#define SCAN_NB  49          // ceil((NN+1)/1024)
#define GEMM_NB  1563        // (NN+31)/32
#define HIST_NB  3125        // EE / 256

__device__ __forceinline__ ushortT f2bf(float f) {
    uintT u = __float_as_uint(f);
    u = (u + 0x7fff + ((u >> 16) & 1)) >> 16;   // RNE
    return (ushortT)u;
}
__device__ __forceinline__ float bflo(uintT u) { return __uint_as_float(u << 16); }
__device__ __forceinline__ float bfhi(uintT u) { return __uint_as_float(u & 0xffff0000u); }

// convert Wl|Wr to bf16: wbf[256][128], rows 0..127 = Wl, 128..255 = Wr
__global__ __launch_bounds__(256) void wprep_kernel(
    const float* __restrict__ Wl, const float* __restrict__ Wr, ushortT* __restrict__ wbf)
{
    const int i = blockIdx.x * 256 + threadIdx.x;   // 4096 threads, 8 elems each
    const float* src = (i < 2048) ? Wl : Wr;
    const int off = (i < 2048) ? i : i - 2048;
    const float4 v0 = *(const float4*)(src + (size_t)off * 8);
    const float4 v1 = *(const float4*)(src + (size_t)off * 8 + 4);
    bf16x8 o;
    o[0] = f2bf(v0.x); o[1] = f2bf(v0.y); o[2] = f2bf(v0.z); o[3] = f2bf(v0.w);
    o[4] = f2bf(v1.x); o[5] = f2bf(v1.y); o[6] = f2bf(v1.z); o[7] = f2bf(v1.w);
    *(bf16x8*)(wbf + ((i < 2048) ? 0 : 16384) + (size_t)off * 8) = o;
}

// ---------------------------------------------------------------------------
// COMBO: blocks [0,GEMM_NB) = MFMA gemm; [GEMM_NB, +HIST_NB) = hist+rank.
// hist's atomicAdd RETURN VALUE is the edge's unique rank within its dst
// segment -> the later scatter needs no atomics at all.
// ---------------------------------------------------------------------------
__global__ __launch_bounds__(256) void combo_kernel(
    const float* __restrict__ x, const ushortT* __restrict__ wbf,
    ushortT* __restrict__ xph, const int* __restrict__ ei_raw,
    int* __restrict__ cnt, int* __restrict__ rank)
{
    __shared__ ushortT smem[9216];        // 18.4 KB: xa[32][136] then tl[4][32][72]
    __shared__ int sflag;
    const int t = threadIdx.x;

    if (blockIdx.x >= GEMM_NB) {
        // ---- histogram + rank path ----
        if (t < 64) {
            const int w = ei_raw[2 * t + 1];
            const unsigned long long b = __ballot(w != 0);
            if (t == 0) sflag = (b == 0ULL) ? 1 : 0;
        }
        __syncthreads();
        const int e = (blockIdx.x - GEMM_NB) * 256 + t;
        if (e < EE) {
            const int d = sflag ? ei_raw[2 * (EE + e)] : ei_raw[EE + e];
            rank[e] = atomicAdd(&cnt[d], 1);
        }
        return;
    }

    // ---- gemm path ----
    ushortT (*xa)[136] = (ushortT(*)[136])smem;          // 4352 ushorts
    ushortT (*tl)[32][72] = (ushortT(*)[32][72])smem;    // 9216 ushorts (aliased)
    const int row0 = blockIdx.x * 32;

    {   // stage + convert 32 rows of x
        const int r = t >> 3, seg = t & 7;
        const int gr = row0 + r;
        const int gr_c = gr < NN ? gr : NN - 1;
        const float* src = x + (size_t)gr_c * CIN + seg * 16;
        const float4 v0 = *(const float4*)(src);
        const float4 v1 = *(const float4*)(src + 4);
        const float4 v2 = *(const float4*)(src + 8);
        const float4 v3 = *(const float4*)(src + 12);
        bf16x8 o0, o1;
        o0[0] = f2bf(v0.x); o0[1] = f2bf(v0.y); o0[2] = f2bf(v0.z); o0[3] = f2bf(v0.w);
        o0[4] = f2bf(v1.x); o0[5] = f2bf(v1.y); o0[6] = f2bf(v1.z); o0[7] = f2bf(v1.w);
        o1[0] = f2bf(v2.x); o1[1] = f2bf(v2.y); o1[2] = f2bf(v2.z); o1[3] = f2bf(v2.w);
        o1[4] = f2bf(v3.x); o1[5] = f2bf(v3.y); o1[6] = f2bf(v3.z); o1[7] = f2bf(v3.w);
        *(bf16x8*)(&xa[r][seg * 16]) = o0;
        *(bf16x8*)(&xa[r][seg * 16 + 8]) = o1;
    }
    __syncthreads();

    const int w = t >> 6, l = t & 63;
    const int part = w >> 1, ch = w & 1;
    const int rowlo = l & 15, kb = (l >> 4) * 8;

    bf16x8 a[2][4];
    #pragma unroll
    for (int rg = 0; rg < 2; ++rg)
        #pragma unroll
        for (int ks = 0; ks < 4; ++ks)
            a[rg][ks] = *(const bf16x8*)(&xa[rg * 16 + rowlo][ks * 32 + kb]);
    __syncthreads();    // all xa reads done before tl overwrites the buffer

    f32x4 acc[2][4] = {};
    const ushortT* wbase = wbf + (size_t)(part * 128 + ch * 64 + rowlo) * 128 + kb;
    #pragma unroll
    for (int ks = 0; ks < 4; ++ks) {
        #pragma unroll
        for (int ct = 0; ct < 4; ++ct) {
            const bf16x8 b = *(const bf16x8*)(wbase + (size_t)ct * 16 * 128 + ks * 32);
            acc[0][ct] = __builtin_amdgcn_mfma_f32_16x16x32_bf16(a[0][ks], b, acc[0][ct], 0, 0, 0);
            acc[1][ct] = __builtin_amdgcn_mfma_f32_16x16x32_bf16(a[1][ks], b, acc[1][ct], 0, 0, 0);
        }
    }

    #pragma unroll
    for (int rg = 0; rg < 2; ++rg)
        #pragma unroll
        for (int ct = 0; ct < 4; ++ct)
            #pragma unroll
            for (int j = 0; j < 4; ++j)
                tl[w][rg * 16 + (l >> 4) * 4 + j][ct * 16 + rowlo] = f2bf(acc[rg][ct][j]);
    __syncthreads();

    #pragma unroll
    for (int c = 0; c < 4; ++c) {
        const int cid = c * 256 + t;
        const int r = cid >> 5, col = (cid & 31) * 8;
        const int gr = row0 + r;
        if (gr < NN)
            *(bf16x8*)(xph + (size_t)gr * 256 + col) =
                *(const bf16x8*)(&tl[col >> 6][r][col & 63]);
    }
}

// ---------------------------------------------------------------------------
// scan1: block-local exclusive scan of cnt; btot[b] = block total
// ---------------------------------------------------------------------------
__global__ __launch_bounds__(1024) void scan1_kernel(
    const int* __restrict__ cnt, int* __restrict__ row, int* __restrict__ btot)
{
    __shared__ int wtot[16];
    const int t = threadIdx.x, lane = t & 63, wv = t >> 6;
    const int i = blockIdx.x * 1024 + t;
    const int v = (i < NN) ? cnt[i] : 0;
    int acc = v;
    #pragma unroll
    for (int off = 1; off < 64; off <<= 1) {
        const int u = __shfl_up(acc, off, 64);
        if (lane >= off) acc += u;
    }
    if (lane == 63) wtot[wv] = acc;
    __syncthreads();
    if (wv == 0 && lane < 16) {
        const int wvv = wtot[lane];
        int wacc = wvv;
        #pragma unroll
        for (int off = 1; off < 16; off <<= 1) {
            const int u = __shfl_up(wacc, off, 64);
            if (lane >= off) wacc += u;
        }
        wtot[lane] = wacc - wvv;            // exclusive wave offset
    }
    __syncthreads();
    const int ex = wtot[wv] + acc - v;      // block-local exclusive prefix
    if (i <= NN) row[i] = ex;
    if (t == 1023) btot[blockIdx.x] = ex + v;
}

// scan2: btot -> exclusive prefix (1 block, 64 threads)
__global__ void scan2_kernel(int* __restrict__ btot)
{
    const int lane = threadIdx.x;
    const int v = (lane < SCAN_NB) ? btot[lane] : 0;
    int acc = v;
    #pragma unroll
    for (int off = 1; off < 64; off <<= 1) {
        const int u = __shfl_up(acc, off, 64);
        if (lane >= off) acc += u;
    }
    if (lane < SCAN_NB) btot[lane] = acc - v;          // exclusive
}

// atomic-free scatter: pos = row[d] + btot[d>>10] + rank[e]
__global__ __launch_bounds__(256) void scatter_kernel(
    const int* __restrict__ ei_raw, const int* __restrict__ row,
    const int* __restrict__ btot, const int* __restrict__ rank,
    int* __restrict__ esrc)
{
    __shared__ int sflag;
    const int t = threadIdx.x;
    if (t < 64) {
        const int w = ei_raw[2 * t + 1];
        const unsigned long long b = __ballot(w != 0);
        if (t == 0) sflag = (b == 0ULL) ? 1 : 0;
    }
    __syncthreads();
    const int e = blockIdx.x * 256 + t;
    if (e < EE) {
        int s, d;
        if (sflag) { s = ei_raw[2 * e]; d = ei_raw[2 * (EE + e)]; }
        else       { s = ei_raw[e];     d = ei_raw[EE + e]; }
        esrc[row[d] + btot[d >> 10] + rank[e]] = s;
    }
}

// ---------------------------------------------------------------------------
// Fused per-node GATv2 (r12-proven): one wave per node, lane = h*16+dd,
// self-loop inline, main loop unrolled 8 (16 gathers in flight).
// ---------------------------------------------------------------------------
#define SCORE_OF(ulv, cv)                                                 \
    {                                                                     \
        float vx = bflo(ulv) + rnx, vy = bfhi(ulv) + rny;                 \
        vx = vx > 0.f ? vx : NEG * vx;                                    \
        vy = vy > 0.f ? vy : NEG * vy;                                    \
        cv = vx * a2.x + vy * a2.y;                                       \
    }
#define RED16(cv)                                                         \
    cv += __shfl_xor(cv, 1); cv += __shfl_xor(cv, 2);                     \
    cv += __shfl_xor(cv, 4); cv += __shfl_xor(cv, 8);

#define GROUP4(i0, i1, i2, i3)                                            \
    {                                                                     \
        float c0, c1, c2, c3;                                             \
        SCORE_OF(ul[i0], c0) SCORE_OF(ul[i1], c1)                         \
        SCORE_OF(ul[i2], c2) SCORE_OF(ul[i3], c3)                         \
        c0 += __shfl_xor(c0, 1); c1 += __shfl_xor(c1, 1);                 \
        c2 += __shfl_xor(c2, 1); c3 += __shfl_xor(c3, 1);                 \
        c0 += __shfl_xor(c0, 2); c1 += __shfl_xor(c1, 2);                 \
        c2 += __shfl_xor(c2, 2); c3 += __shfl_xor(c3, 2);                 \
        c0 += __shfl_xor(c0, 4); c1 += __shfl_xor(c1, 4);                 \
        c2 += __shfl_xor(c2, 4); c3 += __shfl_xor(c3, 4);                 \
        c0 += __shfl_xor(c0, 8); c1 += __shfl_xor(c1, 8);                 \
        c2 += __shfl_xor(c2, 8); c3 += __shfl_xor(c3, 8);                 \
        const float e0 = __expf(c0), e1 = __expf(c1);                     \
        const float e2 = __expf(c2), e3 = __expf(c3);                     \
        den += (e0 + e1) + (e2 + e3);                                     \
        ax = fmaf(e0, bflo(us[i0]), ax); ay = fmaf(e0, bfhi(us[i0]), ay); \
        ax = fmaf(e1, bflo(us[i1]), ax); ay = fmaf(e1, bfhi(us[i1]), ay); \
        ax = fmaf(e2, bflo(us[i2]), ax); ay = fmaf(e2, bfhi(us[i2]), ay); \
        ax = fmaf(e3, bflo(us[i3]), ax); ay = fmaf(e3, bfhi(us[i3]), ay); \
    }

__global__ __launch_bounds__(256) void gat_node_kernel(
    const int* __restrict__ row, const int* __restrict__ btot,
    const int* __restrict__ esrc, const ushortT* __restrict__ xph,
    const float* __restrict__ att, const float* __restrict__ bias,
    float* __restrict__ out)
{
    const int lane = threadIdx.x & 63;
    const int h = lane >> 4, dd = lane & 15;
    const int n = blockIdx.x * 4 + (threadIdx.x >> 6);
    if (n >= NN) return;

    const float2 a2 = *(const float2*)(att + h * DD + dd * 2);
    const uintT uln = *(const uintT*)(xph + (size_t)n * 256 + lane * 2);
    const uintT urn = *(const uintT*)(xph + (size_t)n * 256 + 128 + lane * 2);
    const float rnx = bflo(urn), rny = bfhi(urn);

    // self-loop first
    float den, ax, ay;
    {
        float c;
        SCORE_OF(uln, c)
        RED16(c)
        const float pe = __expf(c);
        den = pe;
        ax = pe * bflo(urn);
        ay = pe * bfhi(urn);
    }

    const int p0 = row[n] + btot[n >> 10];
    const int p1 = row[n + 1] + btot[(n + 1) >> 10];
    int p = p0;

    for (; p + 8 <= p1; p += 8) {
        int s[8];
        #pragma unroll
        for (int j = 0; j < 8; ++j) s[j] = esrc[p + j];
        uintT ul[8], us[8];
        #pragma unroll
        for (int j = 0; j < 8; ++j) {
            ul[j] = *(const uintT*)(xph + (size_t)s[j] * 256 + lane * 2);
            us[j] = *(const uintT*)(xph + (size_t)s[j] * 256 + 128 + lane * 2);
        }
        GROUP4(0, 1, 2, 3) GROUP4(4, 5, 6, 7)
    }
    for (; p + 4 <= p1; p += 4) {
        int s[4];
        #pragma unroll
        for (int j = 0; j < 4; ++j) s[j] = esrc[p + j];
        uintT ul[4], us[4];
        #pragma unroll
        for (int j = 0; j < 4; ++j) {
            ul[j] = *(const uintT*)(xph + (size_t)s[j] * 256 + lane * 2);
            us[j] = *(const uintT*)(xph + (size_t)s[j] * 256 + 128 + lane * 2);
        }
        GROUP4(0, 1, 2, 3)
    }
    for (; p < p1; ++p) {
        const int s = esrc[p];
        const uintT ul = *(const uintT*)(xph + (size_t)s * 256 + lane * 2);
        const uintT us = *(const uintT*)(xph + (size_t)s * 256 + 128 + lane * 2);
        float c;
        SCORE_OF(ul, c)
        RED16(c)
        const float pe = __expf(c);
        den += pe;
        ax = fmaf(pe, bflo(us), ax);
        ay = fmaf(pe, bfhi(us), ay);
    }

    const float inv = 1.f / fmaxf(den, 1e-16f);
    ax *= inv; ay *= inv;
    ax += __shfl_xor(ax, 16); ay += __shfl_xor(ay, 16);
    ax += __shfl_xor(ax, 32); ay += __shfl_xor(ay, 32);
    if (h == 0) {
        float2 o;
        o.x = ax * 0.25f + bias[dd * 2];
        o.y = ay * 0.25f + bias[dd * 2 + 1];
        *(float2*)(out + (size_t)n * DD + dd * 2) = o;
    }
}

extern "C" void kernel_launch(void* const* d_in, const int* in_sizes, int n_in,
                              void* d_out, int out_size, void* d_ws, size_t ws_size,
                              hipStream_t stream)
{
    const float* x    = (const float*)d_in[0];
    const int*   ei   = (const int*)d_in[1];
    const float* Wl   = (const float*)d_in[2];
    const float* Wr   = (const float*)d_in[3];
    const float* att  = (const float*)d_in[4];
    const float* bias = (const float*)d_in[5];
    float* out = (float*)d_out;

    float*   ws   = (float*)d_ws;
    int*     cnt  = (int*)(ws + CNT_OFF);
    int*     row  = (int*)(ws + ROW_OFF);
    int*     rank = (int*)(ws + RANK_OFF);
    int*     esrc = (int*)(ws + ESRC_OFF);
    int*     btot = (int*)(ws + BTOT_OFF);
    ushortT* wbf  = (ushortT*)(ws + WBF_OFF);
    ushortT* xph  = (ushortT*)(ws + XPH_OFF);

    // zero cnt (200 KB)
    hipMemsetAsync(cnt, 0, (size_t)NN * sizeof(int), stream);

    hipLaunchKernelGGL(wprep_kernel, dim3(16), dim3(256), 0, stream, Wl, Wr, wbf);
    hipLaunchKernelGGL(combo_kernel, dim3(GEMM_NB + HIST_NB), dim3(256), 0, stream,
                       x, wbf, xph, ei, cnt, rank);
    hipLaunchKernelGGL(scan1_kernel, dim3(SCAN_NB), dim3(1024), 0, stream, cnt, row, btot);
    hipLaunchKernelGGL(scan2_kernel, dim3(1), dim3(64), 0, stream, btot);
    hipLaunchKernelGGL(scatter_kernel, dim3(HIST_NB), dim3(256), 0, stream,
                       ei, row, btot, rank, esrc);
    hipLaunchKernelGGL(gat_node_kernel, dim3((NN + 3) / 4), dim3(256), 0, stream,
                       row, btot, esrc, xph, att, bias, out);
}

// Round 19
// 130.238 us; speedup vs baseline: 1.5395x; 1.0661x over previous
//
#include <hip/hip_runtime.h>
#include <hip/hip_bf16.h>

#define NN 50000
#define CIN 128
#define HH 4
#define DD 32
#define HD 128
#define EE 800000
#define NEG 0.2f

typedef unsigned short ushortT;
typedef unsigned int uintT;
typedef __attribute__((ext_vector_type(8))) short bf16x8;
typedef __attribute__((ext_vector_type(4))) float f32x4;

// ---------------------------------------------------------------------------
// ws layout (units of 4B):
//   CNT_OFF  = 16       : per-node in-degree (excl self) (NN ints) [memset 0]
//   ROW_OFF  = 50016    : CSR row offsets, block-local (NN+1 ints)
//   RANK_OFF = 100032   : per-edge rank within dst segment (EE ints)
//   ESRC_OFF = 900048   : dst-sorted src indices (EE ints)
//   BTOT_OFF = 1700064  : scan block totals -> exclusive prefix (64 ints)
//   WBF_OFF  = 1700128  : W bf16 [256][128] (16384 float-slots)
//   XPH_OFF  = 1716512  : interleaved bf16 rows xl|xr [NN][256] (3.2M slots)
// ---------------------------------------------------------------------------
#define CNT_OFF  16
#define ROW_OFF  50016
#define RANK_OFF 100032
#define ESRC_OFF 900048
#define BTOT_OFF 1700064
#define WBF_OFF  1700128
#define XPH_OFF  1716512
#define SCAN_NB  49          // ceil((NN+1)/1024)
#define GEMM_NB  1563        // (NN+31)/32
#define HIST_NB  782         // ceil(EE / (256*4))
#define TOT_NB   2346        // 3 * HIST_NB = GEMM_NB+1 (pad) + HIST_NB

__device__ __forceinline__ ushortT f2bf(float f) {
    uintT u = __float_as_uint(f);
    u = (u + 0x7fff + ((u >> 16) & 1)) >> 16;   // RNE
    return (ushortT)u;
}
__device__ __forceinline__ float bflo(uintT u) { return __uint_as_float(u << 16); }
__device__ __forceinline__ float bfhi(uintT u) { return __uint_as_float(u & 0xffff0000u); }

// convert Wl|Wr to bf16: wbf[256][128], rows 0..127 = Wl, 128..255 = Wr
__global__ __launch_bounds__(256) void wprep_kernel(
    const float* __restrict__ Wl, const float* __restrict__ Wr, ushortT* __restrict__ wbf)
{
    const int i = blockIdx.x * 256 + threadIdx.x;   // 4096 threads, 8 elems each
    const float* src = (i < 2048) ? Wl : Wr;
    const int off = (i < 2048) ? i : i - 2048;
    const float4 v0 = *(const float4*)(src + (size_t)off * 8);
    const float4 v1 = *(const float4*)(src + (size_t)off * 8 + 4);
    bf16x8 o;
    o[0] = f2bf(v0.x); o[1] = f2bf(v0.y); o[2] = f2bf(v0.z); o[3] = f2bf(v0.w);
    o[4] = f2bf(v1.x); o[5] = f2bf(v1.y); o[6] = f2bf(v1.z); o[7] = f2bf(v1.w);
    *(bf16x8*)(wbf + ((i < 2048) ? 0 : 16384) + (size_t)off * 8) = o;
}

// ---------------------------------------------------------------------------
// COMBO, INTERLEAVED roles: blockIdx%3 ∈ {0,1} -> gemm (gid=(b/3)*2+b%3),
// blockIdx%3 == 2 -> hist (hid=b/3, 4 edges/thread, rank = atomic return).
// Both cohorts co-resident from t=0 -> true resource overlap
// (gemm: MFMA + HBM streams; hist: fabric atomics).
// ---------------------------------------------------------------------------
__global__ __launch_bounds__(256) void combo_kernel(
    const float* __restrict__ x, const ushortT* __restrict__ wbf,
    ushortT* __restrict__ xph, const int* __restrict__ ei_raw,
    int* __restrict__ cnt, int* __restrict__ rank)
{
    __shared__ ushortT smem[9216];        // 18.4 KB: xa[32][136] then tl[4][32][72]
    __shared__ int sflag;
    const int t = threadIdx.x;
    const int role = blockIdx.x % 3;

    if (role == 2) {
        // ---- histogram + rank path (4 edges/thread) ----
        if (t < 64) {
            const int w = ei_raw[2 * t + 1];
            const unsigned long long b = __ballot(w != 0);
            if (t == 0) sflag = (b == 0ULL) ? 1 : 0;
        }
        __syncthreads();
        const int f = sflag;
        const int t0 = (blockIdx.x / 3) * 256 + t;
        const int stride = HIST_NB * 256;
        #pragma unroll
        for (int k = 0; k < 4; ++k) {
            const int e = t0 + k * stride;
            if (e < EE) {
                const int d = f ? ei_raw[2 * (EE + e)] : ei_raw[EE + e];
                rank[e] = atomicAdd(&cnt[d], 1);
            }
        }
        return;
    }

    // ---- gemm path ----
    const int gid = (blockIdx.x / 3) * 2 + role;
    if (gid >= GEMM_NB) return;           // pad block
    ushortT (*xa)[136] = (ushortT(*)[136])smem;          // 4352 ushorts
    ushortT (*tl)[32][72] = (ushortT(*)[32][72])smem;    // 9216 ushorts (aliased)
    const int row0 = gid * 32;

    {   // stage + convert 32 rows of x
        const int r = t >> 3, seg = t & 7;
        const int gr = row0 + r;
        const int gr_c = gr < NN ? gr : NN - 1;
        const float* src = x + (size_t)gr_c * CIN + seg * 16;
        const float4 v0 = *(const float4*)(src);
        const float4 v1 = *(const float4*)(src + 4);
        const float4 v2 = *(const float4*)(src + 8);
        const float4 v3 = *(const float4*)(src + 12);
        bf16x8 o0, o1;
        o0[0] = f2bf(v0.x); o0[1] = f2bf(v0.y); o0[2] = f2bf(v0.z); o0[3] = f2bf(v0.w);
        o0[4] = f2bf(v1.x); o0[5] = f2bf(v1.y); o0[6] = f2bf(v1.z); o0[7] = f2bf(v1.w);
        o1[0] = f2bf(v2.x); o1[1] = f2bf(v2.y); o1[2] = f2bf(v2.z); o1[3] = f2bf(v2.w);
        o1[4] = f2bf(v3.x); o1[5] = f2bf(v3.y); o1[6] = f2bf(v3.z); o1[7] = f2bf(v3.w);
        *(bf16x8*)(&xa[r][seg * 16]) = o0;
        *(bf16x8*)(&xa[r][seg * 16 + 8]) = o1;
    }
    __syncthreads();

    const int w = t >> 6, l = t & 63;
    const int part = w >> 1, ch = w & 1;
    const int rowlo = l & 15, kb = (l >> 4) * 8;

    bf16x8 a[2][4];
    #pragma unroll
    for (int rg = 0; rg < 2; ++rg)
        #pragma unroll
        for (int ks = 0; ks < 4; ++ks)
            a[rg][ks] = *(const bf16x8*)(&xa[rg * 16 + rowlo][ks * 32 + kb]);
    __syncthreads();    // all xa reads done before tl overwrites the buffer

    f32x4 acc[2][4] = {};
    const ushortT* wbase = wbf + (size_t)(part * 128 + ch * 64 + rowlo) * 128 + kb;
    #pragma unroll
    for (int ks = 0; ks < 4; ++ks) {
        #pragma unroll
        for (int ct = 0; ct < 4; ++ct) {
            const bf16x8 b = *(const bf16x8*)(wbase + (size_t)ct * 16 * 128 + ks * 32);
            acc[0][ct] = __builtin_amdgcn_mfma_f32_16x16x32_bf16(a[0][ks], b, acc[0][ct], 0, 0, 0);
            acc[1][ct] = __builtin_amdgcn_mfma_f32_16x16x32_bf16(a[1][ks], b, acc[1][ct], 0, 0, 0);
        }
    }

    #pragma unroll
    for (int rg = 0; rg < 2; ++rg)
        #pragma unroll
        for (int ct = 0; ct < 4; ++ct)
            #pragma unroll
            for (int j = 0; j < 4; ++j)
                tl[w][rg * 16 + (l >> 4) * 4 + j][ct * 16 + rowlo] = f2bf(acc[rg][ct][j]);
    __syncthreads();

    #pragma unroll
    for (int c = 0; c < 4; ++c) {
        const int cid = c * 256 + t;
        const int r = cid >> 5, col = (cid & 31) * 8;
        const int gr = row0 + r;
        if (gr < NN)
            *(bf16x8*)(xph + (size_t)gr * 256 + col) =
                *(const bf16x8*)(&tl[col >> 6][r][col & 63]);
    }
}

// ---------------------------------------------------------------------------
// scan1: block-local exclusive scan of cnt; btot[b] = block total
// ---------------------------------------------------------------------------
__global__ __launch_bounds__(1024) void scan1_kernel(
    const int* __restrict__ cnt, int* __restrict__ row, int* __restrict__ btot)
{
    __shared__ int wtot[16];
    const int t = threadIdx.x, lane = t & 63, wv = t >> 6;
    const int i = blockIdx.x * 1024 + t;
    const int v = (i < NN) ? cnt[i] : 0;
    int acc = v;
    #pragma unroll
    for (int off = 1; off < 64; off <<= 1) {
        const int u = __shfl_up(acc, off, 64);
        if (lane >= off) acc += u;
    }
    if (lane == 63) wtot[wv] = acc;
    __syncthreads();
    if (wv == 0 && lane < 16) {
        const int wvv = wtot[lane];
        int wacc = wvv;
        #pragma unroll
        for (int off = 1; off < 16; off <<= 1) {
            const int u = __shfl_up(wacc, off, 64);
            if (lane >= off) wacc += u;
        }
        wtot[lane] = wacc - wvv;            // exclusive wave offset
    }
    __syncthreads();
    const int ex = wtot[wv] + acc - v;      // block-local exclusive prefix
    if (i <= NN) row[i] = ex;
    if (t == 1023) btot[blockIdx.x] = ex + v;
}

// scan2: btot -> exclusive prefix (1 block, 64 threads)
__global__ void scan2_kernel(int* __restrict__ btot)
{
    const int lane = threadIdx.x;
    const int v = (lane < SCAN_NB) ? btot[lane] : 0;
    int acc = v;
    #pragma unroll
    for (int off = 1; off < 64; off <<= 1) {
        const int u = __shfl_up(acc, off, 64);
        if (lane >= off) acc += u;
    }
    if (lane < SCAN_NB) btot[lane] = acc - v;          // exclusive
}

// atomic-free scatter, 4 edges/thread: pos = row[d] + btot[d>>10] + rank[e]
__global__ __launch_bounds__(256) void scatter_kernel(
    const int* __restrict__ ei_raw, const int* __restrict__ row,
    const int* __restrict__ btot, const int* __restrict__ rank,
    int* __restrict__ esrc)
{
    __shared__ int sflag;
    const int t = threadIdx.x;
    if (t < 64) {
        const int w = ei_raw[2 * t + 1];
        const unsigned long long b = __ballot(w != 0);
        if (t == 0) sflag = (b == 0ULL) ? 1 : 0;
    }
    __syncthreads();
    const int f = sflag;
    const int t0 = blockIdx.x * 256 + t;
    const int stride = gridDim.x * 256;
    #pragma unroll
    for (int k = 0; k < 4; ++k) {
        const int e = t0 + k * stride;
        if (e < EE) {
            int s, d;
            if (f) { s = ei_raw[2 * e]; d = ei_raw[2 * (EE + e)]; }
            else   { s = ei_raw[e];     d = ei_raw[EE + e]; }
            esrc[row[d] + btot[d >> 10] + rank[e]] = s;
        }
    }
}

// ---------------------------------------------------------------------------
// Fused per-node GATv2 (r12-proven): one wave per node, lane = h*16+dd,
// self-loop inline, main loop unrolled 8 (16 gathers in flight).
// ---------------------------------------------------------------------------
#define SCORE_OF(ulv, cv)                                                 \
    {                                                                     \
        float vx = bflo(ulv) + rnx, vy = bfhi(ulv) + rny;                 \
        vx = vx > 0.f ? vx : NEG * vx;                                    \
        vy = vy > 0.f ? vy : NEG * vy;                                    \
        cv = vx * a2.x + vy * a2.y;                                       \
    }
#define RED16(cv)                                                         \
    cv += __shfl_xor(cv, 1); cv += __shfl_xor(cv, 2);                     \
    cv += __shfl_xor(cv, 4); cv += __shfl_xor(cv, 8);

#define GROUP4(i0, i1, i2, i3)                                            \
    {                                                                     \
        float c0, c1, c2, c3;                                             \
        SCORE_OF(ul[i0], c0) SCORE_OF(ul[i1], c1)                         \
        SCORE_OF(ul[i2], c2) SCORE_OF(ul[i3], c3)                         \
        c0 += __shfl_xor(c0, 1); c1 += __shfl_xor(c1, 1);                 \
        c2 += __shfl_xor(c2, 1); c3 += __shfl_xor(c3, 1);                 \
        c0 += __shfl_xor(c0, 2); c1 += __shfl_xor(c1, 2);                 \
        c2 += __shfl_xor(c2, 2); c3 += __shfl_xor(c3, 2);                 \
        c0 += __shfl_xor(c0, 4); c1 += __shfl_xor(c1, 4);                 \
        c2 += __shfl_xor(c2, 4); c3 += __shfl_xor(c3, 4);                 \
        c0 += __shfl_xor(c0, 8); c1 += __shfl_xor(c1, 8);                 \
        c2 += __shfl_xor(c2, 8); c3 += __shfl_xor(c3, 8);                 \
        const float e0 = __expf(c0), e1 = __expf(c1);                     \
        const float e2 = __expf(c2), e3 = __expf(c3);                     \
        den += (e0 + e1) + (e2 + e3);                                     \
        ax = fmaf(e0, bflo(us[i0]), ax); ay = fmaf(e0, bfhi(us[i0]), ay); \
        ax = fmaf(e1, bflo(us[i1]), ax); ay = fmaf(e1, bfhi(us[i1]), ay); \
        ax = fmaf(e2, bflo(us[i2]), ax); ay = fmaf(e2, bfhi(us[i2]), ay); \
        ax = fmaf(e3, bflo(us[i3]), ax); ay = fmaf(e3, bfhi(us[i3]), ay); \
    }

__global__ __launch_bounds__(256) void gat_node_kernel(
    const int* __restrict__ row, const int* __restrict__ btot,
    const int* __restrict__ esrc, const ushortT* __restrict__ xph,
    const float* __restrict__ att, const float* __restrict__ bias,
    float* __restrict__ out)
{
    const int lane = threadIdx.x & 63;
    const int h = lane >> 4, dd = lane & 15;
    const int n = blockIdx.x * 4 + (threadIdx.x >> 6);
    if (n >= NN) return;

    const float2 a2 = *(const float2*)(att + h * DD + dd * 2);
    const uintT uln = *(const uintT*)(xph + (size_t)n * 256 + lane * 2);
    const uintT urn = *(const uintT*)(xph + (size_t)n * 256 + 128 + lane * 2);
    const float rnx = bflo(urn), rny = bfhi(urn);

    // self-loop first
    float den, ax, ay;
    {
        float c;
        SCORE_OF(uln, c)
        RED16(c)
        const float pe = __expf(c);
        den = pe;
        ax = pe * bflo(urn);
        ay = pe * bfhi(urn);
    }

    const int p0 = row[n] + btot[n >> 10];
    const int p1 = row[n + 1] + btot[(n + 1) >> 10];
    int p = p0;

    for (; p + 8 <= p1; p += 8) {
        int s[8];
        #pragma unroll
        for (int j = 0; j < 8; ++j) s[j] = esrc[p + j];
        uintT ul[8], us[8];
        #pragma unroll
        for (int j = 0; j < 8; ++j) {
            ul[j] = *(const uintT*)(xph + (size_t)s[j] * 256 + lane * 2);
            us[j] = *(const uintT*)(xph + (size_t)s[j] * 256 + 128 + lane * 2);
        }
        GROUP4(0, 1, 2, 3) GROUP4(4, 5, 6, 7)
    }
    for (; p + 4 <= p1; p += 4) {
        int s[4];
        #pragma unroll
        for (int j = 0; j < 4; ++j) s[j] = esrc[p + j];
        uintT ul[4], us[4];
        #pragma unroll
        for (int j = 0; j < 4; ++j) {
            ul[j] = *(const uintT*)(xph + (size_t)s[j] * 256 + lane * 2);
            us[j] = *(const uintT*)(xph + (size_t)s[j] * 256 + 128 + lane * 2);
        }
        GROUP4(0, 1, 2, 3)
    }
    for (; p < p1; ++p) {
        const int s = esrc[p];
        const uintT ul = *(const uintT*)(xph + (size_t)s * 256 + lane * 2);
        const uintT us = *(const uintT*)(xph + (size_t)s * 256 + 128 + lane * 2);
        float c;
        SCORE_OF(ul, c)
        RED16(c)
        const float pe = __expf(c);
        den += pe;
        ax = fmaf(pe, bflo(us), ax);
        ay = fmaf(pe, bfhi(us), ay);
    }

    const float inv = 1.f / fmaxf(den, 1e-16f);
    ax *= inv; ay *= inv;
    ax += __shfl_xor(ax, 16); ay += __shfl_xor(ay, 16);
    ax += __shfl_xor(ax, 32); ay += __shfl_xor(ay, 32);
    if (h == 0) {
        float2 o;
        o.x = ax * 0.25f + bias[dd * 2];
        o.y = ay * 0.25f + bias[dd * 2 + 1];
        *(float2*)(out + (size_t)n * DD + dd * 2) = o;
    }
}

extern "C" void kernel_launch(void* const* d_in, const int* in_sizes, int n_in,
                              void* d_out, int out_size, void* d_ws, size_t ws_size,
                              hipStream_t stream)
{
    const float* x    = (const float*)d_in[0];
    const int*   ei   = (const int*)d_in[1];
    const float* Wl   = (const float*)d_in[2];
    const float* Wr   = (const float*)d_in[3];
    const float* att  = (const float*)d_in[4];
    const float* bias = (const float*)d_in[5];
    float* out = (float*)d_out;

    float*   ws   = (float*)d_ws;
    int*     cnt  = (int*)(ws + CNT_OFF);
    int*     row  = (int*)(ws + ROW_OFF);
    int*     rank = (int*)(ws + RANK_OFF);
    int*     esrc = (int*)(ws + ESRC_OFF);
    int*     btot = (int*)(ws + BTOT_OFF);
    ushortT* wbf  = (ushortT*)(ws + WBF_OFF);
    ushortT* xph  = (ushortT*)(ws + XPH_OFF);

    // zero cnt (200 KB)
    hipMemsetAsync(cnt, 0, (size_t)NN * sizeof(int), stream);

    hipLaunchKernelGGL(wprep_kernel, dim3(16), dim3(256), 0, stream, Wl, Wr, wbf);
    hipLaunchKernelGGL(combo_kernel, dim3(TOT_NB), dim3(256), 0, stream,
                       x, wbf, xph, ei, cnt, rank);
    hipLaunchKernelGGL(scan1_kernel, dim3(SCAN_NB), dim3(1024), 0, stream, cnt, row, btot);
    hipLaunchKernelGGL(scan2_kernel, dim3(1), dim3(64), 0, stream, btot);
    hipLaunchKernelGGL(scatter_kernel, dim3(HIST_NB), dim3(256), 0, stream,
                       ei, row, btot, rank, esrc);
    hipLaunchKernelGGL(gat_node_kernel, dim3((NN + 3) / 4), dim3(256), 0, stream,
                       row, btot, esrc, xph, att, bias, out);
}

// Round 20
// 127.444 us; speedup vs baseline: 1.5733x; 1.0219x over previous
//
#include <hip/hip_runtime.h>
#include <hip/hip_bf16.h>

#define NN 50000
#define CIN 128
#define HH 4
#define DD 32
#define HD 128
#define EE 800000
#define NEG 0.2f

typedef unsigned short ushortT;
typedef unsigned int uintT;
typedef __attribute__((ext_vector_type(8))) short bf16x8;
typedef __attribute__((ext_vector_type(4))) float f32x4;

// ---------------------------------------------------------------------------
// ws layout (units of 4B):
//   CNT_OFF  = 16       : per-node in-degree (excl self) (NN ints) [zeroed by wprep]
//   ROW_OFF  = 50016    : CSR row offsets, block-local (NN+1 ints)
//   RANK_OFF = 100032   : per-edge rank within dst segment (EE ints)
//   ESRC_OFF = 900048   : dst-sorted src indices (EE ints)
//   BTOT_OFF = 1700064  : scan block totals (RAW, 64 ints)
//   WBF_OFF  = 1700128  : W bf16 [256][128] (16384 float-slots)
//   XPH_OFF  = 1716512  : interleaved bf16 rows xl|xr [NN][256] (3.2M slots)
// ---------------------------------------------------------------------------
#define CNT_OFF  16
#define ROW_OFF  50016
#define RANK_OFF 100032
#define ESRC_OFF 900048
#define BTOT_OFF 1700064
#define WBF_OFF  1700128
#define XPH_OFF  1716512
#define SCAN_NB  49          // ceil((NN+1)/1024)
#define GEMM_NB  1563        // (NN+31)/32
#define HIST_NB  782         // ceil(EE / (256*4))
#define TOT_NB   2346        // 3 * HIST_NB

__device__ __forceinline__ ushortT f2bf(float f) {
    uintT u = __float_as_uint(f);
    u = (u + 0x7fff + ((u >> 16) & 1)) >> 16;   // RNE
    return (ushortT)u;
}
__device__ __forceinline__ float bflo(uintT u) { return __uint_as_float(u << 16); }
__device__ __forceinline__ float bfhi(uintT u) { return __uint_as_float(u & 0xffff0000u); }

// convert Wl|Wr to bf16 AND zero cnt (replaces the memset dispatch)
__global__ __launch_bounds__(256) void wprep_kernel(
    const float* __restrict__ Wl, const float* __restrict__ Wr,
    ushortT* __restrict__ wbf, int* __restrict__ cnt)
{
    const int i = blockIdx.x * 256 + threadIdx.x;   // 4096 threads
    const float* src = (i < 2048) ? Wl : Wr;
    const int off = (i < 2048) ? i : i - 2048;
    const float4 v0 = *(const float4*)(src + (size_t)off * 8);
    const float4 v1 = *(const float4*)(src + (size_t)off * 8 + 4);
    bf16x8 o;
    o[0] = f2bf(v0.x); o[1] = f2bf(v0.y); o[2] = f2bf(v0.z); o[3] = f2bf(v0.w);
    o[4] = f2bf(v1.x); o[5] = f2bf(v1.y); o[6] = f2bf(v1.z); o[7] = f2bf(v1.w);
    *(bf16x8*)(wbf + ((i < 2048) ? 0 : 16384) + (size_t)off * 8) = o;
    for (int j = i; j < NN; j += 4096) cnt[j] = 0;
}

// ---------------------------------------------------------------------------
// COMBO, INTERLEAVED roles: blockIdx%3 ∈ {0,1} -> gemm (gid=(b/3)*2+b%3),
// blockIdx%3 == 2 -> hist (4 edges/thread, rank = atomic return value).
// ---------------------------------------------------------------------------
__global__ __launch_bounds__(256) void combo_kernel(
    const float* __restrict__ x, const ushortT* __restrict__ wbf,
    ushortT* __restrict__ xph, const int* __restrict__ ei_raw,
    int* __restrict__ cnt, int* __restrict__ rank)
{
    __shared__ ushortT smem[9216];        // 18.4 KB: xa[32][136] then tl[4][32][72]
    __shared__ int sflag;
    const int t = threadIdx.x;
    const int role = blockIdx.x % 3;

    if (role == 2) {
        // ---- histogram + rank path (4 edges/thread) ----
        if (t < 64) {
            const int w = ei_raw[2 * t + 1];
            const unsigned long long b = __ballot(w != 0);
            if (t == 0) sflag = (b == 0ULL) ? 1 : 0;
        }
        __syncthreads();
        const int f = sflag;
        const int t0 = (blockIdx.x / 3) * 256 + t;
        const int stride = HIST_NB * 256;
        #pragma unroll
        for (int k = 0; k < 4; ++k) {
            const int e = t0 + k * stride;
            if (e < EE) {
                const int d = f ? ei_raw[2 * (EE + e)] : ei_raw[EE + e];
                rank[e] = atomicAdd(&cnt[d], 1);
            }
        }
        return;
    }

    // ---- gemm path ----
    const int gid = (blockIdx.x / 3) * 2 + role;
    if (gid >= GEMM_NB) return;           // pad block
    ushortT (*xa)[136] = (ushortT(*)[136])smem;          // 4352 ushorts
    ushortT (*tl)[32][72] = (ushortT(*)[32][72])smem;    // 9216 ushorts (aliased)
    const int row0 = gid * 32;

    {   // stage + convert 32 rows of x
        const int r = t >> 3, seg = t & 7;
        const int gr = row0 + r;
        const int gr_c = gr < NN ? gr : NN - 1;
        const float* src = x + (size_t)gr_c * CIN + seg * 16;
        const float4 v0 = *(const float4*)(src);
        const float4 v1 = *(const float4*)(src + 4);
        const float4 v2 = *(const float4*)(src + 8);
        const float4 v3 = *(const float4*)(src + 12);
        bf16x8 o0, o1;
        o0[0] = f2bf(v0.x); o0[1] = f2bf(v0.y); o0[2] = f2bf(v0.z); o0[3] = f2bf(v0.w);
        o0[4] = f2bf(v1.x); o0[5] = f2bf(v1.y); o0[6] = f2bf(v1.z); o0[7] = f2bf(v1.w);
        o1[0] = f2bf(v2.x); o1[1] = f2bf(v2.y); o1[2] = f2bf(v2.z); o1[3] = f2bf(v2.w);
        o1[4] = f2bf(v3.x); o1[5] = f2bf(v3.y); o1[6] = f2bf(v3.z); o1[7] = f2bf(v3.w);
        *(bf16x8*)(&xa[r][seg * 16]) = o0;
        *(bf16x8*)(&xa[r][seg * 16 + 8]) = o1;
    }
    __syncthreads();

    const int w = t >> 6, l = t & 63;
    const int part = w >> 1, ch = w & 1;
    const int rowlo = l & 15, kb = (l >> 4) * 8;

    bf16x8 a[2][4];
    #pragma unroll
    for (int rg = 0; rg < 2; ++rg)
        #pragma unroll
        for (int ks = 0; ks < 4; ++ks)
            a[rg][ks] = *(const bf16x8*)(&xa[rg * 16 + rowlo][ks * 32 + kb]);
    __syncthreads();    // all xa reads done before tl overwrites the buffer

    f32x4 acc[2][4] = {};
    const ushortT* wbase = wbf + (size_t)(part * 128 + ch * 64 + rowlo) * 128 + kb;
    #pragma unroll
    for (int ks = 0; ks < 4; ++ks) {
        #pragma unroll
        for (int ct = 0; ct < 4; ++ct) {
            const bf16x8 b = *(const bf16x8*)(wbase + (size_t)ct * 16 * 128 + ks * 32);
            acc[0][ct] = __builtin_amdgcn_mfma_f32_16x16x32_bf16(a[0][ks], b, acc[0][ct], 0, 0, 0);
            acc[1][ct] = __builtin_amdgcn_mfma_f32_16x16x32_bf16(a[1][ks], b, acc[1][ct], 0, 0, 0);
        }
    }

    #pragma unroll
    for (int rg = 0; rg < 2; ++rg)
        #pragma unroll
        for (int ct = 0; ct < 4; ++ct)
            #pragma unroll
            for (int j = 0; j < 4; ++j)
                tl[w][rg * 16 + (l >> 4) * 4 + j][ct * 16 + rowlo] = f2bf(acc[rg][ct][j]);
    __syncthreads();

    #pragma unroll
    for (int c = 0; c < 4; ++c) {
        const int cid = c * 256 + t;
        const int r = cid >> 5, col = (cid & 31) * 8;
        const int gr = row0 + r;
        if (gr < NN)
            *(bf16x8*)(xph + (size_t)gr * 256 + col) =
                *(const bf16x8*)(&tl[col >> 6][r][col & 63]);
    }
}

// ---------------------------------------------------------------------------
// scan1: block-local exclusive scan of cnt; btot[b] = RAW block total
// ---------------------------------------------------------------------------
__global__ __launch_bounds__(1024) void scan1_kernel(
    const int* __restrict__ cnt, int* __restrict__ row, int* __restrict__ btot)
{
    __shared__ int wtot[16];
    const int t = threadIdx.x, lane = t & 63, wv = t >> 6;
    const int i = blockIdx.x * 1024 + t;
    const int v = (i < NN) ? cnt[i] : 0;
    int acc = v;
    #pragma unroll
    for (int off = 1; off < 64; off <<= 1) {
        const int u = __shfl_up(acc, off, 64);
        if (lane >= off) acc += u;
    }
    if (lane == 63) wtot[wv] = acc;
    __syncthreads();
    if (wv == 0 && lane < 16) {
        const int wvv = wtot[lane];
        int wacc = wvv;
        #pragma unroll
        for (int off = 1; off < 16; off <<= 1) {
            const int u = __shfl_up(wacc, off, 64);
            if (lane >= off) wacc += u;
        }
        wtot[lane] = wacc - wvv;            // exclusive wave offset
    }
    __syncthreads();
    const int ex = wtot[wv] + acc - v;      // block-local exclusive prefix
    if (i <= NN) row[i] = ex;
    if (t == 1023) btot[blockIdx.x] = ex + v;
}

// atomic-free scatter, 4 edges/thread; btot prefix built in LDS per block
__global__ __launch_bounds__(256) void scatter_kernel(
    const int* __restrict__ ei_raw, const int* __restrict__ row,
    const int* __restrict__ btot, const int* __restrict__ rank,
    int* __restrict__ esrc)
{
    __shared__ int sflag;
    __shared__ int pref[64];
    const int t = threadIdx.x;
    if (t < 64) {
        const int w = ei_raw[2 * t + 1];
        const unsigned long long b = __ballot(w != 0);
        if (t == 0) sflag = (b == 0ULL) ? 1 : 0;
        // exclusive prefix of raw btot (49 entries) in-wave
        const int v = (t < SCAN_NB) ? btot[t] : 0;
        int acc = v;
        #pragma unroll
        for (int off = 1; off < 64; off <<= 1) {
            const int u = __shfl_up(acc, off, 64);
            if (t >= off) acc += u;
        }
        pref[t] = acc - v;
    }
    __syncthreads();
    const int f = sflag;
    const int t0 = blockIdx.x * 256 + t;
    const int stride = gridDim.x * 256;
    #pragma unroll
    for (int k = 0; k < 4; ++k) {
        const int e = t0 + k * stride;
        if (e < EE) {
            int s, d;
            if (f) { s = ei_raw[2 * e]; d = ei_raw[2 * (EE + e)]; }
            else   { s = ei_raw[e];     d = ei_raw[EE + e]; }
            esrc[row[d] + pref[d >> 10] + rank[e]] = s;
        }
    }
}

// ---------------------------------------------------------------------------
// Fused per-node GATv2: 128-thread blocks (2 nodes) to cut degree-imbalance
// tail; wave-inline btot prefix (n>>10 is wave-uniform); unrolled 8.
// ---------------------------------------------------------------------------
#define SCORE_OF(ulv, cv)                                                 \
    {                                                                     \
        float vx = bflo(ulv) + rnx, vy = bfhi(ulv) + rny;                 \
        vx = vx > 0.f ? vx : NEG * vx;                                    \
        vy = vy > 0.f ? vy : NEG * vy;                                    \
        cv = vx * a2.x + vy * a2.y;                                       \
    }
#define RED16(cv)                                                         \
    cv += __shfl_xor(cv, 1); cv += __shfl_xor(cv, 2);                     \
    cv += __shfl_xor(cv, 4); cv += __shfl_xor(cv, 8);

#define GROUP4(i0, i1, i2, i3)                                            \
    {                                                                     \
        float c0, c1, c2, c3;                                             \
        SCORE_OF(ul[i0], c0) SCORE_OF(ul[i1], c1)                         \
        SCORE_OF(ul[i2], c2) SCORE_OF(ul[i3], c3)                         \
        c0 += __shfl_xor(c0, 1); c1 += __shfl_xor(c1, 1);                 \
        c2 += __shfl_xor(c2, 1); c3 += __shfl_xor(c3, 1);                 \
        c0 += __shfl_xor(c0, 2); c1 += __shfl_xor(c1, 2);                 \
        c2 += __shfl_xor(c2, 2); c3 += __shfl_xor(c3, 2);                 \
        c0 += __shfl_xor(c0, 4); c1 += __shfl_xor(c1, 4);                 \
        c2 += __shfl_xor(c2, 4); c3 += __shfl_xor(c3, 4);                 \
        c0 += __shfl_xor(c0, 8); c1 += __shfl_xor(c1, 8);                 \
        c2 += __shfl_xor(c2, 8); c3 += __shfl_xor(c3, 8);                 \
        const float e0 = __expf(c0), e1 = __expf(c1);                     \
        const float e2 = __expf(c2), e3 = __expf(c3);                     \
        den += (e0 + e1) + (e2 + e3);                                     \
        ax = fmaf(e0, bflo(us[i0]), ax); ay = fmaf(e0, bfhi(us[i0]), ay); \
        ax = fmaf(e1, bflo(us[i1]), ax); ay = fmaf(e1, bfhi(us[i1]), ay); \
        ax = fmaf(e2, bflo(us[i2]), ax); ay = fmaf(e2, bfhi(us[i2]), ay); \
        ax = fmaf(e3, bflo(us[i3]), ax); ay = fmaf(e3, bfhi(us[i3]), ay); \
    }

__global__ __launch_bounds__(128) void gat_node_kernel(
    const int* __restrict__ row, const int* __restrict__ btot,
    const int* __restrict__ esrc, const ushortT* __restrict__ xph,
    const float* __restrict__ att, const float* __restrict__ bias,
    float* __restrict__ out)
{
    const int lane = threadIdx.x & 63;
    const int h = lane >> 4, dd = lane & 15;
    const int n = blockIdx.x * 2 + (threadIdx.x >> 6);
    if (n >= NN) return;

    // wave-inline exclusive prefix of raw btot at chunk c1 = n>>10
    const int c1 = n >> 10;
    int pv = (lane < c1) ? btot[lane] : 0;
    #pragma unroll
    for (int off = 1; off < 64; off <<= 1) pv += __shfl_xor(pv, off);
    const int c2 = (n + 1) >> 10;
    const int pre2 = pv + ((c2 > c1) ? btot[c1] : 0);

    const float2 a2 = *(const float2*)(att + h * DD + dd * 2);
    const uintT uln = *(const uintT*)(xph + (size_t)n * 256 + lane * 2);
    const uintT urn = *(const uintT*)(xph + (size_t)n * 256 + 128 + lane * 2);
    const float rnx = bflo(urn), rny = bfhi(urn);

    // self-loop first
    float den, ax, ay;
    {
        float c;
        SCORE_OF(uln, c)
        RED16(c)
        const float pe = __expf(c);
        den = pe;
        ax = pe * bflo(urn);
        ay = pe * bfhi(urn);
    }

    const int p0 = row[n] + pv;
    const int p1 = row[n + 1] + pre2;
    int p = p0;

    for (; p + 8 <= p1; p += 8) {
        int s[8];
        #pragma unroll
        for (int j = 0; j < 8; ++j) s[j] = esrc[p + j];
        uintT ul[8], us[8];
        #pragma unroll
        for (int j = 0; j < 8; ++j) {
            ul[j] = *(const uintT*)(xph + (size_t)s[j] * 256 + lane * 2);
            us[j] = *(const uintT*)(xph + (size_t)s[j] * 256 + 128 + lane * 2);
        }
        GROUP4(0, 1, 2, 3) GROUP4(4, 5, 6, 7)
    }
    for (; p + 4 <= p1; p += 4) {
        int s[4];
        #pragma unroll
        for (int j = 0; j < 4; ++j) s[j] = esrc[p + j];
        uintT ul[4], us[4];
        #pragma unroll
        for (int j = 0; j < 4; ++j) {
            ul[j] = *(const uintT*)(xph + (size_t)s[j] * 256 + lane * 2);
            us[j] = *(const uintT*)(xph + (size_t)s[j] * 256 + 128 + lane * 2);
        }
        GROUP4(0, 1, 2, 3)
    }
    for (; p < p1; ++p) {
        const int s = esrc[p];
        const uintT ul = *(const uintT*)(xph + (size_t)s * 256 + lane * 2);
        const uintT us = *(const uintT*)(xph + (size_t)s * 256 + 128 + lane * 2);
        float c;
        SCORE_OF(ul, c)
        RED16(c)
        const float pe = __expf(c);
        den += pe;
        ax = fmaf(pe, bflo(us), ax);
        ay = fmaf(pe, bfhi(us), ay);
    }

    const float inv = 1.f / fmaxf(den, 1e-16f);
    ax *= inv; ay *= inv;
    ax += __shfl_xor(ax, 16); ay += __shfl_xor(ay, 16);
    ax += __shfl_xor(ax, 32); ay += __shfl_xor(ay, 32);
    if (h == 0) {
        float2 o;
        o.x = ax * 0.25f + bias[dd * 2];
        o.y = ay * 0.25f + bias[dd * 2 + 1];
        *(float2*)(out + (size_t)n * DD + dd * 2) = o;
    }
}

extern "C" void kernel_launch(void* const* d_in, const int* in_sizes, int n_in,
                              void* d_out, int out_size, void* d_ws, size_t ws_size,
                              hipStream_t stream)
{
    const float* x    = (const float*)d_in[0];
    const int*   ei   = (const int*)d_in[1];
    const float* Wl   = (const float*)d_in[2];
    const float* Wr   = (const float*)d_in[3];
    const float* att  = (const float*)d_in[4];
    const float* bias = (const float*)d_in[5];
    float* out = (float*)d_out;

    float*   ws   = (float*)d_ws;
    int*     cnt  = (int*)(ws + CNT_OFF);
    int*     row  = (int*)(ws + ROW_OFF);
    int*     rank = (int*)(ws + RANK_OFF);
    int*     esrc = (int*)(ws + ESRC_OFF);
    int*     btot = (int*)(ws + BTOT_OFF);
    ushortT* wbf  = (ushortT*)(ws + WBF_OFF);
    ushortT* xph  = (ushortT*)(ws + XPH_OFF);

    hipLaunchKernelGGL(wprep_kernel, dim3(16), dim3(256), 0, stream, Wl, Wr, wbf, cnt);
    hipLaunchKernelGGL(combo_kernel, dim3(TOT_NB), dim3(256), 0, stream,
                       x, wbf, xph, ei, cnt, rank);
    hipLaunchKernelGGL(scan1_kernel, dim3(SCAN_NB), dim3(1024), 0, stream, cnt, row, btot);
    hipLaunchKernelGGL(scatter_kernel, dim3(HIST_NB), dim3(256), 0, stream,
                       ei, row, btot, rank, esrc);
    hipLaunchKernelGGL(gat_node_kernel, dim3((NN + 1) / 2), dim3(128), 0, stream,
                       row, btot, esrc, xph, att, bias, out);
}